// Round 14
// baseline (1283.241 us; speedup 1.0000x reference)
//
#include <hip/hip_runtime.h>
#include <math.h>

#define NVAR  20000
#define NVAL  160000
#define NCST  20000
#define NEDGE 160000
#define HD    128
#define NT16  10000    // NVAL/16 row-tiles

typedef __attribute__((ext_vector_type(8))) short  short8;   // 8 bf16 (4 VGPRs)
typedef __attribute__((ext_vector_type(4))) float  f32x4;    // MFMA accumulator
typedef __attribute__((ext_vector_type(4))) float  floatx4;

// fast gates (2% tolerance)
static __device__ __forceinline__ float sigf(float x) {
    return __fdividef(1.0f, 1.0f + __expf(-x));
}
static __device__ __forceinline__ float tanhf_(float x) {
    return 1.0f - __fdividef(2.0f, 1.0f + __expf(2.0f * x));
}

static __device__ __forceinline__ short bf16c(float f) {   // RNE f32->bf16
    unsigned u = __float_as_uint(f);
    u += 0x7fffu + ((u >> 16) & 1u);
    return (short)(u >> 16);
}
static __device__ __forceinline__ float bf2f(unsigned short b) {
    return __uint_as_float(((unsigned)b) << 16);
}
static __device__ __forceinline__ short8 pack8(floatx4 a, floatx4 b) {
    short8 r;
    r[0] = bf16c(a[0]); r[1] = bf16c(a[1]); r[2] = bf16c(a[2]); r[3] = bf16c(a[3]);
    r[4] = bf16c(b[0]); r[5] = bf16c(b[1]); r[6] = bf16c(b[2]); r[7] = bf16c(b[3]);
    return r;
}

// ---------------------------------------------------------------------------
// one-time weight convert+transpose: W[K][N] f32 -> WT[N][K] bf16
// ---------------------------------------------------------------------------
struct WD  { const float* W; short* WT; int K; int N; int total; };
struct WDs { WD d[6]; };

__global__ __launch_bounds__(256) void k_wconv6(WDs ds) {
    WD d = ds.d[blockIdx.y];
    int i = blockIdx.x * 256 + threadIdx.x;
    if (i >= d.total) return;
    int n = i / d.K, k = i - n * d.K;
    d.WT[i] = bf16c(d.W[(size_t)k * d.N + n]);
}

// one-time: W2cT[n][k] = (W2 @ Wc_top)[k][n] in f32, stored bf16 transposed
__global__ __launch_bounds__(256) void k_w2c(const float* __restrict__ W2,
                                             const float* __restrict__ Wc,
                                             short* __restrict__ W2cT) {
    int i = blockIdx.x * 256 + threadIdx.x;   // 16384
    int n = i >> 7, k = i & 127;
    float s = 0.f;
    for (int m = 0; m < 128; ++m) s += W2[k * 128 + m] * Wc[m * 128 + n];
    W2cT[n * 128 + k] = bf16c(s);
}

// one-time: WcBot permuted for the fused XU kernel's custom k-bijection:
// slot s = kc*32 + hi*8 + j  holds  WcBot[k(hi,kc,j)][n2],
// k(hi,kc,j) = (kc*2 + (j>>2))*16 + hi*4 + (j&3).
__global__ __launch_bounds__(256) void k_wcbp(const float* __restrict__ Wc,
                                              short* __restrict__ WcBP) {
    int i = blockIdx.x * 256 + threadIdx.x;   // 16384
    int n2 = i >> 7, s = i & 127;
    int kc = s >> 5, rem = s & 31, hi2 = rem >> 3, j = rem & 7;
    int k = (kc * 2 + (j >> 2)) * 16 + hi2 * 4 + (j & 3);
    WcBP[n2 * 128 + s] = bf16c(Wc[(size_t)(128 + k) * 128 + n2]);
}

// ---------------------------------------------------------------------------
// CSR inversion of val_idx (one-time); inv stores CONSTRAINT id (e>>3)
// ---------------------------------------------------------------------------
__global__ __launch_bounds__(256) void k_hist(const int* __restrict__ val_idx,
                                              int* __restrict__ deg) {
    int e = blockIdx.x * 256 + threadIdx.x;
    if (e < NEDGE) atomicAdd(&deg[val_idx[e]], 1);
}
__global__ __launch_bounds__(256) void k_scan1(const int* __restrict__ deg,
                                               int* __restrict__ bsum) {
    __shared__ int s[256];
    int i = blockIdx.x * 256 + threadIdx.x;
    s[threadIdx.x] = deg[i];
    __syncthreads();
    for (int o = 128; o > 0; o >>= 1) {
        if (threadIdx.x < o) s[threadIdx.x] += s[threadIdx.x + o];
        __syncthreads();
    }
    if (threadIdx.x == 0) bsum[blockIdx.x] = s[0];
}
__global__ void k_scan2(const int* __restrict__ bsum, int* __restrict__ boff, int nb) {
    if (threadIdx.x == 0 && blockIdx.x == 0) {
        int acc = 0;
        for (int b = 0; b < nb; ++b) { boff[b] = acc; acc += bsum[b]; }
        boff[nb] = acc;
    }
}
__global__ __launch_bounds__(256) void k_scan3(const int* __restrict__ deg,
                                               const int* __restrict__ boff,
                                               int* __restrict__ off,
                                               int* __restrict__ cursor) {
    __shared__ int s[256];
    int i = blockIdx.x * 256 + threadIdx.x;
    int d = deg[i];
    s[threadIdx.x] = d;
    __syncthreads();
    for (int o = 1; o < 256; o <<= 1) {
        int v = s[threadIdx.x];
        if (threadIdx.x >= o) v += s[threadIdx.x - o];
        __syncthreads();
        s[threadIdx.x] = v;
        __syncthreads();
    }
    int excl = s[threadIdx.x] - d + boff[blockIdx.x];
    off[i] = excl;
    cursor[i] = excl;
    if (i == NVAL - 1) off[NVAL] = NEDGE;
}
__global__ __launch_bounds__(256) void k_place(const int* __restrict__ val_idx,
                                               int* __restrict__ cursor,
                                               int* __restrict__ inv) {
    int e = blockIdx.x * 256 + threadIdx.x;
    if (e < NEDGE) {
        int p = atomicAdd(&cursor[val_idx[e]], 1);
        inv[p] = e >> 3;                       // constraint id directly
    }
}

// ---------------------------------------------------------------------------
// small kernels
// ---------------------------------------------------------------------------
__global__ __launch_bounds__(256) void k_init_hb(short* __restrict__ h,
                                                 const float* __restrict__ hinit) {
    size_t i = (size_t)blockIdx.x * 256 + threadIdx.x;
    h[i] = bf16c(hinit[i & (HD - 1)]);
}

__global__ __launch_bounds__(256) void k_sample0(const float* __restrict__ g,
                                                 float* __restrict__ assign,
                                                 float* __restrict__ lp_accum) {
    int v = blockIdx.x * 256 + threadIdx.x;
    float lp = 0.f;
    if (v < NVAR) {
        int choice = 0;
        float bestv = -1e30f;
#pragma unroll
        for (int d = 0; d < 8; ++d) {
            float t = g[v * 8 + d];
            if (t > bestv) { bestv = t; choice = d; }
        }
        lp = -__logf(8.0f);
#pragma unroll
        for (int d = 0; d < 8; ++d) assign[v * 8 + d] = (d == choice) ? 1.f : 0.f;
    }
    __shared__ float sred[256];
    sred[threadIdx.x] = lp;
    __syncthreads();
    for (int o = 128; o > 0; o >>= 1) {
        if (threadIdx.x < o) sred[threadIdx.x] += sred[threadIdx.x + o];
        __syncthreads();
    }
    if (threadIdx.x == 0) atomicAdd(lp_accum, sred[0]);
}

__global__ __launch_bounds__(256) void k_unsat(const float* __restrict__ assign,
                                               const int* __restrict__ val_idx,
                                               int* __restrict__ sat_accum) {
    int c = blockIdx.x * 256 + threadIdx.x;
    int sat = 0;
    if (c < NCST) {
#pragma unroll
        for (int j = 0; j < 8; ++j)
            if (assign[val_idx[c * 8 + j]] > 0.5f) sat = 1;
    }
    __shared__ int sred[256];
    sred[threadIdx.x] = sat;
    __syncthreads();
    for (int o = 128; o > 0; o >>= 1) {
        if (threadIdx.x < o) sred[threadIdx.x] += sred[threadIdx.x + o];
        __syncthreads();
    }
    if (threadIdx.x == 0) atomicAdd(sat_accum, sred[0]);
}

__global__ void k_finalize(const float* __restrict__ lp, const int* __restrict__ sat,
                           float* __restrict__ best, float* __restrict__ out,
                           int s, int S, int mode) {
    float nu = (float)NCST - (float)(*sat);
    if (mode == 0) {
        *best = nu;
    } else {
        out[s] = *lp;
        out[S + s] = nu;
        float b = *best;
        if (nu < b) b = nu;
        *best = b;
        if (s == S - 1) out[2 * S] = b;
    }
}

__global__ void k_report(float* out, float v) {
    for (int i = 0; i < 9; ++i) out[i] = v;
}

// ---------------------------------------------------------------------------
// LDS-B MFMA GEMM, K=128, 128 cols/wave (steps 1, r2c)
// ---------------------------------------------------------------------------
static constexpr int AM_DIRECT = 1, AM_GATHER = 2;
static constexpr int EPI_STORE = 0, EPI_RCST = 1;

template <int A0M, bool BIT, bool RELU, int EPI>
__global__ __launch_bounds__(256)
void k_gemmA(const short* __restrict__ A, const int* __restrict__ aidx,
             const float* __restrict__ abit, const float* __restrict__ w1r128,
             const short* __restrict__ WT, const float* __restrict__ bias0,
             short* __restrict__ outBF, short* __restrict__ rcstOut,
             int nrows) {
    const int tid  = threadIdx.x;
    const int w    = tid >> 6;
    const int lane = tid & 63;
    const int li   = lane & 15;
    const int hi   = lane >> 4;

    __shared__ short blds[128 * 136];
    for (int c2 = tid; c2 < 2048; c2 += 256) {
        int r = c2 >> 4, off = c2 & 15;
        *(short8*)(blds + r * 136 + off * 8) = *(const short8*)(WT + (size_t)r * 128 + off * 8);
    }
    __syncthreads();

    float bv[8];
#pragma unroll
    for (int t = 0; t < 8; ++t) bv[t] = bias0 ? bias0[t * 16 + li] : 0.f;
    float wv[8];
    if constexpr (BIT) {
#pragma unroll
        for (int t = 0; t < 8; ++t) wv[t] = w1r128[t * 16 + li];
    }

    const int nt = nrows >> 4;
    const int stride = gridDim.x * 4;
    for (int rt = blockIdx.x * 4 + w; rt < nt; rt += stride) {
        const int ar = rt * 16 + li;
        int ia = ar;
        if constexpr (A0M == AM_GATHER) ia = aidx[ar];
        const short8* arow = (const short8*)(A + (size_t)ia * HD);

        short8 af[4];
#pragma unroll
        for (int kc = 0; kc < 4; ++kc) af[kc] = arow[kc * 4 + hi];

        f32x4 acc[8];
#pragma unroll
        for (int t = 0; t < 8; ++t) acc[t] = (f32x4){0.f, 0.f, 0.f, 0.f};
#pragma unroll
        for (int kc = 0; kc < 4; ++kc)
#pragma unroll
            for (int t = 0; t < 8; ++t) {
                short8 bf = *(const short8*)(blds + (t * 16 + li) * 136 + kc * 32 + hi * 8);
                acc[t] = __builtin_amdgcn_mfma_f32_16x16x32_bf16(af[kc], bf, acc[t], 0, 0, 0);
            }

        if constexpr (BIT) {
#pragma unroll
            for (int r = 0; r < 4; ++r) {
                int gr = rt * 16 + hi * 4 + r;
                float bitv = abit[aidx[gr]];
#pragma unroll
                for (int t = 0; t < 8; ++t) acc[t][r] += bitv * wv[t];
            }
        }
#pragma unroll
        for (int t = 0; t < 8; ++t)
#pragma unroll
            for (int r = 0; r < 4; ++r) {
                acc[t][r] += bv[t];
                if constexpr (RELU) acc[t][r] = fmaxf(acc[t][r], 0.f);
            }

        if constexpr (EPI == EPI_STORE) {
#pragma unroll
            for (int r = 0; r < 4; ++r) {
                int gr = rt * 16 + hi * 4 + r;
                short* o = outBF + (size_t)gr * HD + li;
#pragma unroll
                for (int t = 0; t < 8; ++t) o[t * 16] = bf16c(acc[t][r]);
            }
        } else {  // EPI_RCST: sum groups of 8 rows
#pragma unroll
            for (int t = 0; t < 8; ++t) {
                float s = acc[t][0] + acc[t][1] + acc[t][2] + acc[t][3];
                s += __shfl_xor(s, 16);
                if (hi == 0)      rcstOut[(size_t)(rt * 2) * HD + t * 16 + li]     = bf16c(s);
                else if (hi == 2) rcstOut[(size_t)(rt * 2 + 1) * HD + t * 16 + li] = bf16c(s);
            }
        }
    }
}

// ---------------------------------------------------------------------------
// fused steps 3a+3b: uV = (relu(h @ Wx + bx)) @ WcBot (operand-swap pass 1 +
// custom k-bijection pass 2; WcBP pre-permuted; exact by k-map invariance)
// ---------------------------------------------------------------------------
__global__ __launch_bounds__(256)
void k_gemmXU(const short* __restrict__ H, const short* __restrict__ WxT,
              const short* __restrict__ WcBP, const float* __restrict__ bx,
              short* __restrict__ uV) {
    const int tid  = threadIdx.x;
    const int w    = tid >> 6;
    const int lane = tid & 63;
    const int li   = lane & 15;
    const int hi   = lane >> 4;

    __shared__ short wx[128 * 136];
    __shared__ short wc[128 * 136];
    for (int c2 = tid; c2 < 2048; c2 += 256) {
        int r = c2 >> 4, off = c2 & 15;
        *(short8*)(wx + r * 136 + off * 8) = *(const short8*)(WxT  + (size_t)r * 128 + off * 8);
        *(short8*)(wc + r * 136 + off * 8) = *(const short8*)(WcBP + (size_t)r * 128 + off * 8);
    }
    __syncthreads();

    float bx32[8][4];
#pragma unroll
    for (int t = 0; t < 8; ++t)
#pragma unroll
        for (int r = 0; r < 4; ++r) bx32[t][r] = bx[t * 16 + hi * 4 + r];

    const int stride = gridDim.x * 4;
    for (int rt = blockIdx.x * 4 + w; rt < NT16; rt += stride) {
        const short8* arow = (const short8*)(H + (size_t)(rt * 16 + li) * HD);
        short8 af[4];
#pragma unroll
        for (int kc = 0; kc < 4; ++kc) af[kc] = arow[kc * 4 + hi];

        f32x4 a1[8];
#pragma unroll
        for (int t = 0; t < 8; ++t) a1[t] = (f32x4){0.f, 0.f, 0.f, 0.f};
#pragma unroll
        for (int kc = 0; kc < 4; ++kc)
#pragma unroll
            for (int t = 0; t < 8; ++t) {
                short8 wf = *(const short8*)(wx + (t * 16 + li) * 136 + kc * 32 + hi * 8);
                a1[t] = __builtin_amdgcn_mfma_f32_16x16x32_bf16(wf, af[kc], a1[t], 0, 0, 0);
            }

        floatx4 xv[8];
#pragma unroll
        for (int t = 0; t < 8; ++t)
#pragma unroll
            for (int r = 0; r < 4; ++r)
                xv[t][r] = fmaxf(a1[t][r] + bx32[t][r], 0.f);

        short8 af2[4];
#pragma unroll
        for (int kc = 0; kc < 4; ++kc) af2[kc] = pack8(xv[2 * kc], xv[2 * kc + 1]);

        f32x4 a2[8];
#pragma unroll
        for (int t = 0; t < 8; ++t) a2[t] = (f32x4){0.f, 0.f, 0.f, 0.f};
#pragma unroll
        for (int kc = 0; kc < 4; ++kc)
#pragma unroll
            for (int t = 0; t < 8; ++t) {
                short8 bf = *(const short8*)(wc + (t * 16 + li) * 136 + kc * 32 + hi * 8);
                a2[t] = __builtin_amdgcn_mfma_f32_16x16x32_bf16(af2[kc], bf, a2[t], 0, 0, 0);
            }

#pragma unroll
        for (int r = 0; r < 4; ++r) {
            int gr = rt * 16 + hi * 4 + r;
            short* o = uV + (size_t)gr * HD + li;
#pragma unroll
            for (int t = 0; t < 8; ++t) o[t * 16] = bf16c(a2[t][r]);
        }
    }
}

// ---------------------------------------------------------------------------
// step 4: wave-per-value CSR gather (deg wave-uniform, no divergence)
// ---------------------------------------------------------------------------
__global__ __launch_bounds__(256)
void k_gather(const short* __restrict__ r2c, const short* __restrict__ uV,
              const int* __restrict__ off, const int* __restrict__ inv,
              const float* __restrict__ bcv, short* __restrict__ yV) {
    const int w    = threadIdx.x >> 6;
    const int lane = threadIdx.x & 63;
    const int c0   = lane * 2;

    const float b0 = bcv[c0], b1 = bcv[c0 + 1];

    for (int v = blockIdx.x * 4 + w; v < NVAL; v += gridDim.x * 4) {
        const int e0 = off[v], e1 = off[v + 1];
        unsigned uu = *(const unsigned*)(uV + (size_t)v * HD + c0);
        const float u0 = bf2f((unsigned short)(uu & 0xffffu)) + b0;
        const float u1 = bf2f((unsigned short)(uu >> 16)) + b1;
        float a0 = 0.f, a1 = 0.f;
        for (int e = e0; e < e1; ++e) {
            const int cst = inv[e];
            unsigned rv = *(const unsigned*)(r2c + (size_t)cst * HD + c0);
            a0 += fmaxf(bf2f((unsigned short)(rv & 0xffffu)) + u0, 0.f);
            a1 += fmaxf(bf2f((unsigned short)(rv >> 16)) + u1, 0.f);
        }
        unsigned o = (unsigned)(unsigned short)bf16c(a0) |
                     ((unsigned)(unsigned short)bf16c(a1) << 16);
        *(unsigned*)(yV + (size_t)v * HD + c0) = o;
    }
}

// ---------------------------------------------------------------------------
// steps 5+6: z = relu([yV | mean8(yV)] @ Wv + bv); B (col-half) in LDS.
// ---------------------------------------------------------------------------
__global__ __launch_bounds__(256)
void k_gemmZ8(const short* __restrict__ yV, const short* __restrict__ WvT,
              const float* __restrict__ bvv, short* __restrict__ outT) {
    const int tid  = threadIdx.x;
    const int w    = tid >> 6;
    const int lane = tid & 63;
    const int li   = lane & 15;
    const int hi   = lane >> 4;
    const int ch   = blockIdx.x & 1;
    const int rba  = blockIdx.x >> 1;

    __shared__ short blds[64 * 264];
    for (int c2 = tid; c2 < 2048; c2 += 256) {
        int r = c2 >> 5, off = c2 & 31;
        *(short8*)(blds + r * 264 + off * 8) =
            *(const short8*)(WvT + (size_t)(ch * 64 + r) * 256 + off * 8);
    }
    __syncthreads();

    float bv[4];
#pragma unroll
    for (int t = 0; t < 4; ++t) bv[t] = bvv[ch * 64 + t * 16 + li];

    for (int rt = rba * 4 + w; rt < NT16; rt += 4096) {
        const int v = rt * 16 + li;
        const short8* yr = (const short8*)(yV + (size_t)v * HD);

        short8 af[8];
        floatx4 m[8];
#pragma unroll
        for (int kc = 0; kc < 4; ++kc) {
            short8 yv = yr[kc * 4 + hi];
            af[kc] = yv;
#pragma unroll
            for (int j = 0; j < 4; ++j) {
                m[2 * kc][j]     = bf2f((unsigned short)yv[j]);
                m[2 * kc + 1][j] = bf2f((unsigned short)yv[4 + j]);
            }
        }
#pragma unroll
        for (int q = 0; q < 8; ++q)
#pragma unroll
            for (int e2 = 0; e2 < 4; ++e2) {
                m[q][e2] += __shfl_xor(m[q][e2], 1);
                m[q][e2] += __shfl_xor(m[q][e2], 2);
                m[q][e2] += __shfl_xor(m[q][e2], 4);
                m[q][e2] *= 0.125f;
            }
#pragma unroll
        for (int kc = 0; kc < 4; ++kc) af[4 + kc] = pack8(m[2 * kc], m[2 * kc + 1]);

        f32x4 acc[4];
#pragma unroll
        for (int t = 0; t < 4; ++t) acc[t] = (f32x4){0.f, 0.f, 0.f, 0.f};
#pragma unroll
        for (int kc = 0; kc < 8; ++kc)
#pragma unroll
            for (int t = 0; t < 4; ++t) {
                short8 bf = *(const short8*)(blds + (t * 16 + li) * 264 + kc * 32 + hi * 8);
                acc[t] = __builtin_amdgcn_mfma_f32_16x16x32_bf16(af[kc], bf, acc[t], 0, 0, 0);
            }

#pragma unroll
        for (int r = 0; r < 4; ++r) {
            int gr = rt * 16 + hi * 4 + r;
            short* o = outT + (size_t)gr * HD + ch * 64 + li;
#pragma unroll
            for (int t = 0; t < 4; ++t)
                o[t * 16] = bf16c(fmaxf(acc[t][r] + bv[t], 0.f));
        }
    }
}

// ---------------------------------------------------------------------------
// GRU, 4-way col-split (R=4): block owns 32 cols (g = bid>>8, SERIAL order —
// measured better cache reuse than concurrent); weight slice 52KB LDS (3
// blocks/CU).  Each wave: 2 col-tiles x 4 gates = 8 indep MFMA chains, 48
// MFMAs/row-tile.  Z/H replication traffic halves vs R=8.
// ---------------------------------------------------------------------------
__global__ __launch_bounds__(256)
void k_gruM(const short* __restrict__ Z, const short* __restrict__ Hold,
            short* __restrict__ Hnew,
            const short* __restrict__ WiT, const short* __restrict__ WhT,
            const float* __restrict__ bi, const float* __restrict__ bh) {
    const int tid  = threadIdx.x;
    const int w    = tid >> 6;
    const int lane = tid & 63;
    const int li   = lane & 15;
    const int hi   = lane >> 4;
    const int g    = blockIdx.x >> 8;     // 0..3 col group (32 cols)
    const int rba  = blockIdx.x & 255;

    // rows 0..95: Wi (3 slabs x 32 cols); rows 96..191: Wh
    __shared__ short blds[192 * 136];
    for (int c2 = tid; c2 < 3072; c2 += 256) {
        int r = c2 >> 4, off = c2 & 15;
        int r2 = (r < 96) ? r : r - 96;
        int sl = r2 >> 5, l = r2 & 31;
        const short* src = ((r < 96) ? WiT : WhT) + (size_t)(sl * 128 + g * 32 + l) * 128 + off * 8;
        *(short8*)(blds + r * 136 + off * 8) = *(const short8*)src;
    }
    __syncthreads();

    float bR[2], bZg[2], bIN[2], bHN[2];
#pragma unroll
    for (int u = 0; u < 2; ++u) {
        int c = g * 32 + u * 16 + li;
        bR[u]  = bi[c] + bh[c];
        bZg[u] = bi[128 + c] + bh[128 + c];
        bIN[u] = bi[256 + c];
        bHN[u] = bh[256 + c];
    }

    const int stride = 1024;              // 256 row-groups * 4 waves
    int rt = rba * 4 + w;
    short8 zf[4], hf[4];
    if (rt < NT16) {
        const short8* zr = (const short8*)(Z    + (size_t)(rt * 16 + li) * HD);
        const short8* hr = (const short8*)(Hold + (size_t)(rt * 16 + li) * HD);
#pragma unroll
        for (int kc = 0; kc < 4; ++kc) { zf[kc] = zr[kc * 4 + hi]; hf[kc] = hr[kc * 4 + hi]; }
    }
    while (rt < NT16) {
        const int rtn = rt + stride;

        f32x4 aR[2], aZ[2], aN[2], aH[2];
#pragma unroll
        for (int u = 0; u < 2; ++u) {
            aR[u] = (f32x4){0.f, 0.f, 0.f, 0.f};
            aZ[u] = (f32x4){0.f, 0.f, 0.f, 0.f};
            aN[u] = (f32x4){0.f, 0.f, 0.f, 0.f};
            aH[u] = (f32x4){0.f, 0.f, 0.f, 0.f};
        }
#pragma unroll
        for (int kc = 0; kc < 4; ++kc) {
            const int ko = kc * 32 + hi * 8;
#pragma unroll
            for (int u = 0; u < 2; ++u) {
                const int cl = u * 16 + li;
                short8 b0 = *(const short8*)(blds + (      cl) * 136 + ko);
                short8 b1 = *(const short8*)(blds + (32  + cl) * 136 + ko);
                short8 b2 = *(const short8*)(blds + (64  + cl) * 136 + ko);
                aR[u] = __builtin_amdgcn_mfma_f32_16x16x32_bf16(zf[kc], b0, aR[u], 0, 0, 0);
                aZ[u] = __builtin_amdgcn_mfma_f32_16x16x32_bf16(zf[kc], b1, aZ[u], 0, 0, 0);
                aN[u] = __builtin_amdgcn_mfma_f32_16x16x32_bf16(zf[kc], b2, aN[u], 0, 0, 0);
            }
        }
#pragma unroll
        for (int kc = 0; kc < 4; ++kc) {
            const int ko = kc * 32 + hi * 8;
#pragma unroll
            for (int u = 0; u < 2; ++u) {
                const int cl = u * 16 + li;
                short8 b0 = *(const short8*)(blds + (96  +      cl) * 136 + ko);
                short8 b1 = *(const short8*)(blds + (96  + 32 + cl) * 136 + ko);
                short8 b2 = *(const short8*)(blds + (96  + 64 + cl) * 136 + ko);
                aR[u] = __builtin_amdgcn_mfma_f32_16x16x32_bf16(hf[kc], b0, aR[u], 0, 0, 0);
                aZ[u] = __builtin_amdgcn_mfma_f32_16x16x32_bf16(hf[kc], b1, aZ[u], 0, 0, 0);
                aH[u] = __builtin_amdgcn_mfma_f32_16x16x32_bf16(hf[kc], b2, aH[u], 0, 0, 0);
            }
        }

        // prefetch next tile's fragments over the gate epilogue
        short8 zfn[4], hfn[4];
        const bool vn = rtn < NT16;
        if (vn) {
            const short8* zr = (const short8*)(Z    + (size_t)(rtn * 16 + li) * HD);
            const short8* hr = (const short8*)(Hold + (size_t)(rtn * 16 + li) * HD);
#pragma unroll
            for (int kc = 0; kc < 4; ++kc) { zfn[kc] = zr[kc * 4 + hi]; hfn[kc] = hr[kc * 4 + hi]; }
        }

#pragma unroll
        for (int r = 0; r < 4; ++r) {
            int gr = rt * 16 + hi * 4 + r;
#pragma unroll
            for (int u = 0; u < 2; ++u) {
                int c = g * 32 + u * 16 + li;
                float hv = bf2f(((const unsigned short*)Hold)[(size_t)gr * HD + c]);
                float rr = sigf(aR[u][r] + bR[u]);
                float zz = sigf(aZ[u][r] + bZg[u]);
                float nn = tanhf_(aN[u][r] + bIN[u] + rr * (aH[u][r] + bHN[u]));
                Hnew[(size_t)gr * HD + c] = bf16c((1.f - zz) * nn + zz * hv);
            }
        }

        if (vn) {
#pragma unroll
            for (int kc = 0; kc < 4; ++kc) { zf[kc] = zfn[kc]; hf[kc] = hfn[kc]; }
        }
        rt = rtn;
    }
}

// ---------------------------------------------------------------------------
// policy + in-wave Gumbel sample; Wp1 in LDS; register lp accumulation.
// ---------------------------------------------------------------------------
__global__ __launch_bounds__(256)
void k_polS(const short* __restrict__ H, const short* __restrict__ Wp1T,
            const float* __restrict__ bp1, const float* __restrict__ Wp2,
            const float* __restrict__ gum_t, float* __restrict__ assign,
            float* __restrict__ lp_acc) {
    const int tid  = threadIdx.x;
    const int w    = tid >> 6;
    const int lane = tid & 63;
    const int li   = lane & 15;
    const int hi   = lane >> 4;

    __shared__ short blds[128 * 136];
    for (int c2 = tid; c2 < 2048; c2 += 256) {
        int r = c2 >> 4, off = c2 & 15;
        *(short8*)(blds + r * 136 + off * 8) = *(const short8*)(Wp1T + (size_t)r * 128 + off * 8);
    }
    __syncthreads();

    float bv[8], wpv[8];
#pragma unroll
    for (int t = 0; t < 8; ++t) { bv[t] = bp1[t * 16 + li]; wpv[t] = Wp2[t * 16 + li]; }

    float lpSum = 0.f;
    const int stride = gridDim.x * 4;
    for (int rt = blockIdx.x * 4 + w; rt < NT16; rt += stride) {
        const short8* arow = (const short8*)(H + (size_t)(rt * 16 + li) * HD);
        short8 af[4];
#pragma unroll
        for (int kc = 0; kc < 4; ++kc) af[kc] = arow[kc * 4 + hi];

        f32x4 acc[8];
#pragma unroll
        for (int t = 0; t < 8; ++t) acc[t] = (f32x4){0.f, 0.f, 0.f, 0.f};
#pragma unroll
        for (int kc = 0; kc < 4; ++kc)
#pragma unroll
            for (int t = 0; t < 8; ++t) {
                short8 bf = *(const short8*)(blds + (t * 16 + li) * 136 + kc * 32 + hi * 8);
                acc[t] = __builtin_amdgcn_mfma_f32_16x16x32_bf16(af[kc], bf, acc[t], 0, 0, 0);
            }

        float lg[4];
#pragma unroll
        for (int r = 0; r < 4; ++r) {
            float p = 0.f;
#pragma unroll
            for (int t = 0; t < 8; ++t) p = fmaf(fmaxf(acc[t][r] + bv[t], 0.f), wpv[t], p);
            p += __shfl_xor(p, 1);
            p += __shfl_xor(p, 2);
            p += __shfl_xor(p, 4);
            p += __shfl_xor(p, 8);
            lg[r] = p;
        }

        float bt = -1e30f, bl = 0.f; int bd = 0;
#pragma unroll
        for (int r = 0; r < 4; ++r) {
            float tv = lg[r] + gum_t[rt * 16 + hi * 4 + r];
            int d = (hi & 1) * 4 + r;
            if (tv > bt) { bt = tv; bl = lg[r]; bd = d; }
        }
        float ot = __shfl_xor(bt, 16);
        float ol = __shfl_xor(bl, 16);
        int   od = __shfl_xor(bd, 16);
        if (ot > bt || (ot == bt && od < bd)) { bt = ot; bl = ol; bd = od; }

        float mx = fmaxf(fmaxf(lg[0], lg[1]), fmaxf(lg[2], lg[3]));
        mx = fmaxf(mx, __shfl_xor(mx, 16));
        float se = __expf(lg[0] - mx) + __expf(lg[1] - mx) +
                   __expf(lg[2] - mx) + __expf(lg[3] - mx);
        se += __shfl_xor(se, 16);

        if (li == 0) {
#pragma unroll
            for (int r = 0; r < 4; ++r)
                assign[rt * 16 + hi * 4 + r] = ((hi & 1) * 4 + r == bd) ? 1.f : 0.f;
            if ((hi & 1) == 0) lpSum += bl - mx - __logf(se);
        }
    }

    __shared__ float sred[256];
    sred[tid] = lpSum;
    __syncthreads();
    for (int o = 128; o > 0; o >>= 1) {
        if (tid < o) sred[tid] += sred[tid + o];
        __syncthreads();
    }
    if (tid == 0) atomicAdd(lp_acc, sred[0]);
}

// ---------------------------------------------------------------------------
extern "C" void kernel_launch(void* const* d_in, const int* in_sizes, int n_in,
                              void* d_out, int out_size, void* d_ws, size_t ws_size,
                              hipStream_t stream) {
    const float* h_init = (const float*)d_in[0];
    const float* W1  = (const float*)d_in[1];
    const float* b1  = (const float*)d_in[2];
    const float* W2  = (const float*)d_in[3];
    const float* Wx  = (const float*)d_in[4];
    const float* bx  = (const float*)d_in[5];
    const float* Wc  = (const float*)d_in[6];
    const float* bc  = (const float*)d_in[7];
    const float* Wv  = (const float*)d_in[8];
    const float* bv  = (const float*)d_in[9];
    const float* Wi  = (const float*)d_in[10];
    const float* Wh  = (const float*)d_in[11];
    const float* bi  = (const float*)d_in[12];
    const float* bh  = (const float*)d_in[13];
    const float* Wp1 = (const float*)d_in[14];
    const float* bp1 = (const float*)d_in[15];
    const float* Wp2 = (const float*)d_in[16];
    const float* gum = (const float*)d_in[17];
    const int* val_idx = (const int*)d_in[18];
    float* out = (float*)d_out;

    const int S = (out_size - 1) / 2;

    const size_t VH = (size_t)NVAL * HD;
    short* hbA   = (short*)d_ws;                      // VH bf16
    short* hbB   = hbA + VH;
    short* tA    = hbB + VH;                          // z
    short* uV    = tA + VH;                           // u_val
    short* yV    = uV + VH;                           // y_val
    short* s_cst = yV + VH;                           // NCST*HD
    short* r2c   = s_cst + (size_t)NCST * HD;         // NCST*HD (L2-resident)
    short* W1T  = r2c + (size_t)NCST * HD;
    short* W2cT = W1T  + 16384;
    short* WxT  = W2cT + 16384;
    short* Wp1T = WxT  + 16384;
    short* WcBP = Wp1T + 16384;                       // permuted WcBot
    short* WvT  = WcBP + 16384;                       // 128 x 256
    short* WiT  = WvT  + 32768;
    short* WhT  = WiT  + 49152;
    float* assign = (float*)(WhT + 49152);            // NVAL
    float* lp_acc = assign + NVAL;                    // 8
    int*   sat    = (int*)(lp_acc + 8);               // 8
    float* best   = (float*)(sat + 8);                // 8
    int*   deg    = (int*)(best + 8);                 // NVAL
    int*   off    = deg + NVAL;                       // NVAL+1
    int*   cursor = off + NVAL + 1;                   // NVAL
    int*   inv    = cursor + NVAL;                    // NEDGE
    int*   bsum   = inv + NEDGE;                      // 625
    int*   boff   = bsum + 625;                       // 626

    const size_t needed = (size_t)((char*)(boff + 626) - (char*)d_ws);
    if (ws_size < needed) {
        k_report<<<1, 1, 0, stream>>>(out, (float)ws_size);
        return;
    }

    // ---- one-time: weights + folds + CSR inversion ----
    WDs ds;
    ds.d[0] = { W1,  W1T,  128, 128, 16384 };
    ds.d[1] = { Wx,  WxT,  128, 128, 16384 };
    ds.d[2] = { Wp1, Wp1T, 128, 128, 16384 };
    ds.d[3] = { Wv,  WvT,  256, 128, 32768 };
    ds.d[4] = { Wi,  WiT,  128, 384, 49152 };
    ds.d[5] = { Wh,  WhT,  128, 384, 49152 };
    k_wconv6<<<dim3(192, 6), dim3(256), 0, stream>>>(ds);
    k_w2c <<<dim3(64), dim3(256), 0, stream>>>(W2, Wc, W2cT);
    k_wcbp<<<dim3(64), dim3(256), 0, stream>>>(Wc, WcBP);

    (void)hipMemsetAsync(lp_acc, 0, 24 * sizeof(float), stream);
    (void)hipMemsetAsync(deg, 0, (size_t)NVAL * sizeof(int), stream);
    k_hist <<<dim3(625), dim3(256), 0, stream>>>(val_idx, deg);
    k_scan1<<<dim3(625), dim3(256), 0, stream>>>(deg, bsum);
    k_scan2<<<1, 1, 0, stream>>>(bsum, boff, 625);
    k_scan3<<<dim3(625), dim3(256), 0, stream>>>(deg, boff, off, cursor);
    k_place<<<dim3(625), dim3(256), 0, stream>>>(val_idx, cursor, inv);

    const dim3 B256(256);
    const dim3 gA(1280);       // K=128 GEMMs over NVAL
    const dim3 gW(320);        // small GEMM over NCST
    const dim3 gXU(512);       // fused x_val->uV
    const dim3 gB(2048);       // Z8 (col-half = bid&1)
    const dim3 gG(1024);       // gruM: 4 col groups (serial) x 256 row blocks
    const dim3 gS(2048);       // gather
    const dim3 gVar((NVAR + 255) / 256);
    const float* w1r128 = W1 + (size_t)128 * HD;

    k_init_hb<<<dim3(NVAL * HD / 256), B256, 0, stream>>>(hbA, h_init);
    k_sample0<<<gVar, B256, 0, stream>>>(gum, assign, lp_acc);
    k_unsat<<<gVar, B256, 0, stream>>>(assign, val_idx, sat);
    k_finalize<<<1, 1, 0, stream>>>(lp_acc, sat, best, out, 0, S, 0);

    for (int s = 0; s < S; ++s) {
        const int t = s + 1;
        const short* hcur = (s & 1) ? hbB : hbA;
        short*       hnxt = (s & 1) ? hbA : hbB;
        // 1. s_cst = sum8(relu([h[val_idx] | bit] @ W1 + b1))
        k_gemmA<AM_GATHER, true, true, EPI_RCST><<<gA, B256, 0, stream>>>(
            hcur, val_idx, assign, w1r128, W1T, b1, nullptr, s_cst, NVAL);
        // 2. r2c = s_cst @ (W2 @ WcTop)
        k_gemmA<AM_DIRECT, false, false, EPI_STORE><<<gW, B256, 0, stream>>>(
            s_cst, nullptr, nullptr, nullptr, W2cT, nullptr, r2c, nullptr, NCST);
        // 3. uV = relu(h @ Wx + bx) @ WcBot   (fused)
        k_gemmXU<<<gXU, B256, 0, stream>>>(hcur, WxT, WcBP, bx, uV);
        // 4. yV = wave-uniform CSR gather of relu(r2c + uV + bc)
        k_gather<<<gS, B256, 0, stream>>>(r2c, uV, off, inv, bc, yV);
        // 5+6. tA = z = relu([yV | mean8(yV)] @ Wv + bv)
        k_gemmZ8<<<gB, B256, 0, stream>>>(yV, WvT, bv, tA);
        // 7. hnxt = GRU(z, hcur)   (R=4 col-split)
        k_gruM<<<gG, B256, 0, stream>>>(tA, hcur, hnxt, WiT, WhT, bi, bh);
        // 8+9a. policy + in-wave sample -> assign, lp
        k_polS<<<gA, B256, 0, stream>>>(hnxt, Wp1T, bp1, Wp2,
                                        gum + (size_t)t * NVAL, assign, lp_acc + t);
        // 9b. unsat + outputs
        k_unsat<<<gVar, B256, 0, stream>>>(assign, val_idx, sat + t);
        k_finalize<<<1, 1, 0, stream>>>(lp_acc + t, sat + t, best, out, s, S, 1);
    }
}

// Round 15
// 1208.644 us; speedup vs baseline: 1.0617x; 1.0617x over previous
//
#include <hip/hip_runtime.h>
#include <math.h>

#define NVAR  20000
#define NVAL  160000
#define NCST  20000
#define NEDGE 160000
#define HD    128
#define NT16  10000    // NVAL/16 row-tiles

typedef __attribute__((ext_vector_type(8))) short  short8;   // 8 bf16 (4 VGPRs)
typedef __attribute__((ext_vector_type(4))) float  f32x4;    // MFMA accumulator
typedef __attribute__((ext_vector_type(4))) float  floatx4;

// fast gates (2% tolerance)
static __device__ __forceinline__ float sigf(float x) {
    return __fdividef(1.0f, 1.0f + __expf(-x));
}
static __device__ __forceinline__ float tanhf_(float x) {
    return 1.0f - __fdividef(2.0f, 1.0f + __expf(2.0f * x));
}

static __device__ __forceinline__ short bf16c(float f) {   // RNE f32->bf16
    unsigned u = __float_as_uint(f);
    u += 0x7fffu + ((u >> 16) & 1u);
    return (short)(u >> 16);
}
static __device__ __forceinline__ float bf2f(unsigned short b) {
    return __uint_as_float(((unsigned)b) << 16);
}
static __device__ __forceinline__ short8 pack8(floatx4 a, floatx4 b) {
    short8 r;
    r[0] = bf16c(a[0]); r[1] = bf16c(a[1]); r[2] = bf16c(a[2]); r[3] = bf16c(a[3]);
    r[4] = bf16c(b[0]); r[5] = bf16c(b[1]); r[6] = bf16c(b[2]); r[7] = bf16c(b[3]);
    return r;
}

// ---------------------------------------------------------------------------
// one-time weight convert+transpose: W[K][N] f32 -> WT[N][K] bf16
// ---------------------------------------------------------------------------
struct WD  { const float* W; short* WT; int K; int N; int total; };
struct WDs { WD d[6]; };

__global__ __launch_bounds__(256) void k_wconv6(WDs ds) {
    WD d = ds.d[blockIdx.y];
    int i = blockIdx.x * 256 + threadIdx.x;
    if (i >= d.total) return;
    int n = i / d.K, k = i - n * d.K;
    d.WT[i] = bf16c(d.W[(size_t)k * d.N + n]);
}

// one-time: W2cT[n][k] = (W2 @ Wc_top)[k][n] in f32, stored bf16 transposed
__global__ __launch_bounds__(256) void k_w2c(const float* __restrict__ W2,
                                             const float* __restrict__ Wc,
                                             short* __restrict__ W2cT) {
    int i = blockIdx.x * 256 + threadIdx.x;   // 16384
    int n = i >> 7, k = i & 127;
    float s = 0.f;
    for (int m = 0; m < 128; ++m) s += W2[k * 128 + m] * Wc[m * 128 + n];
    W2cT[n * 128 + k] = bf16c(s);
}

// one-time: WcBot permuted for the fused XU kernel's custom k-bijection:
// slot s = kc*32 + hi*8 + j  holds  WcBot[k(hi,kc,j)][n2],
// k(hi,kc,j) = (kc*2 + (j>>2))*16 + hi*4 + (j&3).
__global__ __launch_bounds__(256) void k_wcbp(const float* __restrict__ Wc,
                                              short* __restrict__ WcBP) {
    int i = blockIdx.x * 256 + threadIdx.x;   // 16384
    int n2 = i >> 7, s = i & 127;
    int kc = s >> 5, rem = s & 31, hi2 = rem >> 3, j = rem & 7;
    int k = (kc * 2 + (j >> 2)) * 16 + hi2 * 4 + (j & 3);
    WcBP[n2 * 128 + s] = bf16c(Wc[(size_t)(128 + k) * 128 + n2]);
}

// ---------------------------------------------------------------------------
// CSR inversion of val_idx (one-time); inv stores CONSTRAINT id (e>>3)
// ---------------------------------------------------------------------------
__global__ __launch_bounds__(256) void k_hist(const int* __restrict__ val_idx,
                                              int* __restrict__ deg) {
    int e = blockIdx.x * 256 + threadIdx.x;
    if (e < NEDGE) atomicAdd(&deg[val_idx[e]], 1);
}
__global__ __launch_bounds__(256) void k_scan1(const int* __restrict__ deg,
                                               int* __restrict__ bsum) {
    __shared__ int s[256];
    int i = blockIdx.x * 256 + threadIdx.x;
    s[threadIdx.x] = deg[i];
    __syncthreads();
    for (int o = 128; o > 0; o >>= 1) {
        if (threadIdx.x < o) s[threadIdx.x] += s[threadIdx.x + o];
        __syncthreads();
    }
    if (threadIdx.x == 0) bsum[blockIdx.x] = s[0];
}
__global__ void k_scan2(const int* __restrict__ bsum, int* __restrict__ boff, int nb) {
    if (threadIdx.x == 0 && blockIdx.x == 0) {
        int acc = 0;
        for (int b = 0; b < nb; ++b) { boff[b] = acc; acc += bsum[b]; }
        boff[nb] = acc;
    }
}
__global__ __launch_bounds__(256) void k_scan3(const int* __restrict__ deg,
                                               const int* __restrict__ boff,
                                               int* __restrict__ off,
                                               int* __restrict__ cursor) {
    __shared__ int s[256];
    int i = blockIdx.x * 256 + threadIdx.x;
    int d = deg[i];
    s[threadIdx.x] = d;
    __syncthreads();
    for (int o = 1; o < 256; o <<= 1) {
        int v = s[threadIdx.x];
        if (threadIdx.x >= o) v += s[threadIdx.x - o];
        __syncthreads();
        s[threadIdx.x] = v;
        __syncthreads();
    }
    int excl = s[threadIdx.x] - d + boff[blockIdx.x];
    off[i] = excl;
    cursor[i] = excl;
    if (i == NVAL - 1) off[NVAL] = NEDGE;
}
__global__ __launch_bounds__(256) void k_place(const int* __restrict__ val_idx,
                                               int* __restrict__ cursor,
                                               int* __restrict__ inv) {
    int e = blockIdx.x * 256 + threadIdx.x;
    if (e < NEDGE) {
        int p = atomicAdd(&cursor[val_idx[e]], 1);
        inv[p] = e >> 3;                       // constraint id directly
    }
}

// ---------------------------------------------------------------------------
// small kernels
// ---------------------------------------------------------------------------
__global__ __launch_bounds__(256) void k_init_hb(short* __restrict__ h,
                                                 const float* __restrict__ hinit) {
    size_t i = (size_t)blockIdx.x * 256 + threadIdx.x;
    h[i] = bf16c(hinit[i & (HD - 1)]);
}

__global__ __launch_bounds__(256) void k_sample0(const float* __restrict__ g,
                                                 float* __restrict__ assign,
                                                 float* __restrict__ lp_accum) {
    int v = blockIdx.x * 256 + threadIdx.x;
    float lp = 0.f;
    if (v < NVAR) {
        int choice = 0;
        float bestv = -1e30f;
#pragma unroll
        for (int d = 0; d < 8; ++d) {
            float t = g[v * 8 + d];
            if (t > bestv) { bestv = t; choice = d; }
        }
        lp = -__logf(8.0f);
#pragma unroll
        for (int d = 0; d < 8; ++d) assign[v * 8 + d] = (d == choice) ? 1.f : 0.f;
    }
    __shared__ float sred[256];
    sred[threadIdx.x] = lp;
    __syncthreads();
    for (int o = 128; o > 0; o >>= 1) {
        if (threadIdx.x < o) sred[threadIdx.x] += sred[threadIdx.x + o];
        __syncthreads();
    }
    if (threadIdx.x == 0) atomicAdd(lp_accum, sred[0]);
}

__global__ __launch_bounds__(256) void k_unsat(const float* __restrict__ assign,
                                               const int* __restrict__ val_idx,
                                               int* __restrict__ sat_accum) {
    int c = blockIdx.x * 256 + threadIdx.x;
    int sat = 0;
    if (c < NCST) {
#pragma unroll
        for (int j = 0; j < 8; ++j)
            if (assign[val_idx[c * 8 + j]] > 0.5f) sat = 1;
    }
    __shared__ int sred[256];
    sred[threadIdx.x] = sat;
    __syncthreads();
    for (int o = 128; o > 0; o >>= 1) {
        if (threadIdx.x < o) sred[threadIdx.x] += sred[threadIdx.x + o];
        __syncthreads();
    }
    if (threadIdx.x == 0) atomicAdd(sat_accum, sred[0]);
}

__global__ void k_finalize(const float* __restrict__ lp, const int* __restrict__ sat,
                           float* __restrict__ best, float* __restrict__ out,
                           int s, int S, int mode) {
    float nu = (float)NCST - (float)(*sat);
    if (mode == 0) {
        *best = nu;
    } else {
        out[s] = *lp;
        out[S + s] = nu;
        float b = *best;
        if (nu < b) b = nu;
        *best = b;
        if (s == S - 1) out[2 * S] = b;
    }
}

__global__ void k_report(float* out, float v) {
    for (int i = 0; i < 9; ++i) out[i] = v;
}

// ---------------------------------------------------------------------------
// LDS-B MFMA GEMM, K=128, 128 cols/wave (steps 1, r2c)
// ---------------------------------------------------------------------------
static constexpr int AM_DIRECT = 1, AM_GATHER = 2;
static constexpr int EPI_STORE = 0, EPI_RCST = 1;

template <int A0M, bool BIT, bool RELU, int EPI>
__global__ __launch_bounds__(256)
void k_gemmA(const short* __restrict__ A, const int* __restrict__ aidx,
             const float* __restrict__ abit, const float* __restrict__ w1r128,
             const short* __restrict__ WT, const float* __restrict__ bias0,
             short* __restrict__ outBF, short* __restrict__ rcstOut,
             int nrows) {
    const int tid  = threadIdx.x;
    const int w    = tid >> 6;
    const int lane = tid & 63;
    const int li   = lane & 15;
    const int hi   = lane >> 4;

    __shared__ short blds[128 * 136];
    for (int c2 = tid; c2 < 2048; c2 += 256) {
        int r = c2 >> 4, off = c2 & 15;
        *(short8*)(blds + r * 136 + off * 8) = *(const short8*)(WT + (size_t)r * 128 + off * 8);
    }
    __syncthreads();

    float bv[8];
#pragma unroll
    for (int t = 0; t < 8; ++t) bv[t] = bias0 ? bias0[t * 16 + li] : 0.f;
    float wv[8];
    if constexpr (BIT) {
#pragma unroll
        for (int t = 0; t < 8; ++t) wv[t] = w1r128[t * 16 + li];
    }

    const int nt = nrows >> 4;
    const int stride = gridDim.x * 4;
    for (int rt = blockIdx.x * 4 + w; rt < nt; rt += stride) {
        const int ar = rt * 16 + li;
        int ia = ar;
        if constexpr (A0M == AM_GATHER) ia = aidx[ar];
        const short8* arow = (const short8*)(A + (size_t)ia * HD);

        short8 af[4];
#pragma unroll
        for (int kc = 0; kc < 4; ++kc) af[kc] = arow[kc * 4 + hi];

        f32x4 acc[8];
#pragma unroll
        for (int t = 0; t < 8; ++t) acc[t] = (f32x4){0.f, 0.f, 0.f, 0.f};
#pragma unroll
        for (int kc = 0; kc < 4; ++kc)
#pragma unroll
            for (int t = 0; t < 8; ++t) {
                short8 bf = *(const short8*)(blds + (t * 16 + li) * 136 + kc * 32 + hi * 8);
                acc[t] = __builtin_amdgcn_mfma_f32_16x16x32_bf16(af[kc], bf, acc[t], 0, 0, 0);
            }

        if constexpr (BIT) {
#pragma unroll
            for (int r = 0; r < 4; ++r) {
                int gr = rt * 16 + hi * 4 + r;
                float bitv = abit[aidx[gr]];
#pragma unroll
                for (int t = 0; t < 8; ++t) acc[t][r] += bitv * wv[t];
            }
        }
#pragma unroll
        for (int t = 0; t < 8; ++t)
#pragma unroll
            for (int r = 0; r < 4; ++r) {
                acc[t][r] += bv[t];
                if constexpr (RELU) acc[t][r] = fmaxf(acc[t][r], 0.f);
            }

        if constexpr (EPI == EPI_STORE) {
#pragma unroll
            for (int r = 0; r < 4; ++r) {
                int gr = rt * 16 + hi * 4 + r;
                short* o = outBF + (size_t)gr * HD + li;
#pragma unroll
                for (int t = 0; t < 8; ++t) o[t * 16] = bf16c(acc[t][r]);
            }
        } else {  // EPI_RCST: sum groups of 8 rows
#pragma unroll
            for (int t = 0; t < 8; ++t) {
                float s = acc[t][0] + acc[t][1] + acc[t][2] + acc[t][3];
                s += __shfl_xor(s, 16);
                if (hi == 0)      rcstOut[(size_t)(rt * 2) * HD + t * 16 + li]     = bf16c(s);
                else if (hi == 2) rcstOut[(size_t)(rt * 2 + 1) * HD + t * 16 + li] = bf16c(s);
            }
        }
    }
}

// ---------------------------------------------------------------------------
// fused steps 3a+3b: uV = (relu(h @ Wx + bx)) @ WcBot (operand-swap pass 1 +
// custom k-bijection pass 2; WcBP pre-permuted; exact by k-map invariance)
// ---------------------------------------------------------------------------
__global__ __launch_bounds__(256)
void k_gemmXU(const short* __restrict__ H, const short* __restrict__ WxT,
              const short* __restrict__ WcBP, const float* __restrict__ bx,
              short* __restrict__ uV) {
    const int tid  = threadIdx.x;
    const int w    = tid >> 6;
    const int lane = tid & 63;
    const int li   = lane & 15;
    const int hi   = lane >> 4;

    __shared__ short wx[128 * 136];
    __shared__ short wc[128 * 136];
    for (int c2 = tid; c2 < 2048; c2 += 256) {
        int r = c2 >> 4, off = c2 & 15;
        *(short8*)(wx + r * 136 + off * 8) = *(const short8*)(WxT  + (size_t)r * 128 + off * 8);
        *(short8*)(wc + r * 136 + off * 8) = *(const short8*)(WcBP + (size_t)r * 128 + off * 8);
    }
    __syncthreads();

    float bx32[8][4];
#pragma unroll
    for (int t = 0; t < 8; ++t)
#pragma unroll
        for (int r = 0; r < 4; ++r) bx32[t][r] = bx[t * 16 + hi * 4 + r];

    const int stride = gridDim.x * 4;
    for (int rt = blockIdx.x * 4 + w; rt < NT16; rt += stride) {
        const short8* arow = (const short8*)(H + (size_t)(rt * 16 + li) * HD);
        short8 af[4];
#pragma unroll
        for (int kc = 0; kc < 4; ++kc) af[kc] = arow[kc * 4 + hi];

        f32x4 a1[8];
#pragma unroll
        for (int t = 0; t < 8; ++t) a1[t] = (f32x4){0.f, 0.f, 0.f, 0.f};
#pragma unroll
        for (int kc = 0; kc < 4; ++kc)
#pragma unroll
            for (int t = 0; t < 8; ++t) {
                short8 wf = *(const short8*)(wx + (t * 16 + li) * 136 + kc * 32 + hi * 8);
                a1[t] = __builtin_amdgcn_mfma_f32_16x16x32_bf16(wf, af[kc], a1[t], 0, 0, 0);
            }

        floatx4 xv[8];
#pragma unroll
        for (int t = 0; t < 8; ++t)
#pragma unroll
            for (int r = 0; r < 4; ++r)
                xv[t][r] = fmaxf(a1[t][r] + bx32[t][r], 0.f);

        short8 af2[4];
#pragma unroll
        for (int kc = 0; kc < 4; ++kc) af2[kc] = pack8(xv[2 * kc], xv[2 * kc + 1]);

        f32x4 a2[8];
#pragma unroll
        for (int t = 0; t < 8; ++t) a2[t] = (f32x4){0.f, 0.f, 0.f, 0.f};
#pragma unroll
        for (int kc = 0; kc < 4; ++kc)
#pragma unroll
            for (int t = 0; t < 8; ++t) {
                short8 bf = *(const short8*)(wc + (t * 16 + li) * 136 + kc * 32 + hi * 8);
                a2[t] = __builtin_amdgcn_mfma_f32_16x16x32_bf16(af2[kc], bf, a2[t], 0, 0, 0);
            }

#pragma unroll
        for (int r = 0; r < 4; ++r) {
            int gr = rt * 16 + hi * 4 + r;
            short* o = uV + (size_t)gr * HD + li;
#pragma unroll
            for (int t = 0; t < 8; ++t) o[t * 16] = bf16c(a2[t][r]);
        }
    }
}

// ---------------------------------------------------------------------------
// step 4: wave-per-value CSR gather (deg wave-uniform, no divergence)
// ---------------------------------------------------------------------------
__global__ __launch_bounds__(256)
void k_gather(const short* __restrict__ r2c, const short* __restrict__ uV,
              const int* __restrict__ off, const int* __restrict__ inv,
              const float* __restrict__ bcv, short* __restrict__ yV) {
    const int w    = threadIdx.x >> 6;
    const int lane = threadIdx.x & 63;
    const int c0   = lane * 2;

    const float b0 = bcv[c0], b1 = bcv[c0 + 1];

    for (int v = blockIdx.x * 4 + w; v < NVAL; v += gridDim.x * 4) {
        const int e0 = off[v], e1 = off[v + 1];
        unsigned uu = *(const unsigned*)(uV + (size_t)v * HD + c0);
        const float u0 = bf2f((unsigned short)(uu & 0xffffu)) + b0;
        const float u1 = bf2f((unsigned short)(uu >> 16)) + b1;
        float a0 = 0.f, a1 = 0.f;
        for (int e = e0; e < e1; ++e) {
            const int cst = inv[e];
            unsigned rv = *(const unsigned*)(r2c + (size_t)cst * HD + c0);
            a0 += fmaxf(bf2f((unsigned short)(rv & 0xffffu)) + u0, 0.f);
            a1 += fmaxf(bf2f((unsigned short)(rv >> 16)) + u1, 0.f);
        }
        unsigned o = (unsigned)(unsigned short)bf16c(a0) |
                     ((unsigned)(unsigned short)bf16c(a1) << 16);
        *(unsigned*)(yV + (size_t)v * HD + c0) = o;
    }
}

// ---------------------------------------------------------------------------
// steps 5+6: z = relu([yV | mean8(yV)] @ Wv + bv); B (col-half) in LDS.
// ---------------------------------------------------------------------------
__global__ __launch_bounds__(256)
void k_gemmZ8(const short* __restrict__ yV, const short* __restrict__ WvT,
              const float* __restrict__ bvv, short* __restrict__ outT) {
    const int tid  = threadIdx.x;
    const int w    = tid >> 6;
    const int lane = tid & 63;
    const int li   = lane & 15;
    const int hi   = lane >> 4;
    const int ch   = blockIdx.x & 1;
    const int rba  = blockIdx.x >> 1;

    __shared__ short blds[64 * 264];
    for (int c2 = tid; c2 < 2048; c2 += 256) {
        int r = c2 >> 5, off = c2 & 31;
        *(short8*)(blds + r * 264 + off * 8) =
            *(const short8*)(WvT + (size_t)(ch * 64 + r) * 256 + off * 8);
    }
    __syncthreads();

    float bv[4];
#pragma unroll
    for (int t = 0; t < 4; ++t) bv[t] = bvv[ch * 64 + t * 16 + li];

    for (int rt = rba * 4 + w; rt < NT16; rt += 4096) {
        const int v = rt * 16 + li;
        const short8* yr = (const short8*)(yV + (size_t)v * HD);

        short8 af[8];
        floatx4 m[8];
#pragma unroll
        for (int kc = 0; kc < 4; ++kc) {
            short8 yv = yr[kc * 4 + hi];
            af[kc] = yv;
#pragma unroll
            for (int j = 0; j < 4; ++j) {
                m[2 * kc][j]     = bf2f((unsigned short)yv[j]);
                m[2 * kc + 1][j] = bf2f((unsigned short)yv[4 + j]);
            }
        }
#pragma unroll
        for (int q = 0; q < 8; ++q)
#pragma unroll
            for (int e2 = 0; e2 < 4; ++e2) {
                m[q][e2] += __shfl_xor(m[q][e2], 1);
                m[q][e2] += __shfl_xor(m[q][e2], 2);
                m[q][e2] += __shfl_xor(m[q][e2], 4);
                m[q][e2] *= 0.125f;
            }
#pragma unroll
        for (int kc = 0; kc < 4; ++kc) af[4 + kc] = pack8(m[2 * kc], m[2 * kc + 1]);

        f32x4 acc[4];
#pragma unroll
        for (int t = 0; t < 4; ++t) acc[t] = (f32x4){0.f, 0.f, 0.f, 0.f};
#pragma unroll
        for (int kc = 0; kc < 8; ++kc)
#pragma unroll
            for (int t = 0; t < 4; ++t) {
                short8 bf = *(const short8*)(blds + (t * 16 + li) * 264 + kc * 32 + hi * 8);
                acc[t] = __builtin_amdgcn_mfma_f32_16x16x32_bf16(af[kc], bf, acc[t], 0, 0, 0);
            }

#pragma unroll
        for (int r = 0; r < 4; ++r) {
            int gr = rt * 16 + hi * 4 + r;
            short* o = outT + (size_t)gr * HD + ch * 64 + li;
#pragma unroll
            for (int t = 0; t < 4; ++t)
                o[t * 16] = bf16c(fmaxf(acc[t][r] + bv[t], 0.f));
        }
    }
}

// ---------------------------------------------------------------------------
// GRU k_gruN: R=4 traffic + r12 occupancy.  512 thr = 8 waves sharing one
// 52KB LDS slab (32 cols of Wi/Wh); waves 0-3 own low 16-col sub-tile,
// waves 4-7 the high one; each wave = proven 4-acc/100-VGPR inner loop with
// prefetch.  Waves w and w+4 walk identical rows -> L1-shared.  Serial
// col-group order (g = bid>>7, measured better cache reuse).
// ---------------------------------------------------------------------------
__global__ __launch_bounds__(512)
void k_gruN(const short* __restrict__ Z, const short* __restrict__ Hold,
            short* __restrict__ Hnew,
            const short* __restrict__ WiT, const short* __restrict__ WhT,
            const float* __restrict__ bi, const float* __restrict__ bh) {
    const int tid  = threadIdx.x;
    const int w    = tid >> 6;
    const int cu   = w >> 2;              // 0/1: 16-col sub-tile
    const int wr   = w & 3;               // row wave
    const int lane = tid & 63;
    const int li   = lane & 15;
    const int hi   = lane >> 4;
    const int g    = blockIdx.x >> 7;     // 0..3 col group (32 cols), serial
    const int rba  = blockIdx.x & 127;

    // rows 0..95: Wi (3 slabs x 32 cols); rows 96..191: Wh
    __shared__ short blds[192 * 136];
    for (int c2 = tid; c2 < 3072; c2 += 512) {
        int r = c2 >> 4, off = c2 & 15;
        int r2 = (r < 96) ? r : r - 96;
        int sl = r2 >> 5, l = r2 & 31;
        const short* src = ((r < 96) ? WiT : WhT) + (size_t)(sl * 128 + g * 32 + l) * 128 + off * 8;
        *(short8*)(blds + r * 136 + off * 8) = *(const short8*)src;
    }
    __syncthreads();

    const int cl = cu * 16 + li;          // col within the 32-col slab
    const int c  = g * 32 + cl;
    const float bR  = bi[c] + bh[c];
    const float bZg = bi[128 + c] + bh[128 + c];
    const float bIN = bi[256 + c];
    const float bHN = bh[256 + c];

    const int stride = 512;               // 128 row-groups * 4 row-waves
    int rt = rba * 4 + wr;
    short8 zf[4], hf[4];
    if (rt < NT16) {
        const short8* zr = (const short8*)(Z    + (size_t)(rt * 16 + li) * HD);
        const short8* hr = (const short8*)(Hold + (size_t)(rt * 16 + li) * HD);
#pragma unroll
        for (int kc = 0; kc < 4; ++kc) { zf[kc] = zr[kc * 4 + hi]; hf[kc] = hr[kc * 4 + hi]; }
    }
    while (rt < NT16) {
        const int rtn = rt + stride;

        f32x4 aR = {0.f,0.f,0.f,0.f}, aZ = {0.f,0.f,0.f,0.f};
        f32x4 aN = {0.f,0.f,0.f,0.f}, aH = {0.f,0.f,0.f,0.f};
#pragma unroll
        for (int kc = 0; kc < 4; ++kc) {
            const int ko = kc * 32 + hi * 8;
            short8 b0 = *(const short8*)(blds + (      cl) * 136 + ko);
            short8 b1 = *(const short8*)(blds + (32  + cl) * 136 + ko);
            short8 b2 = *(const short8*)(blds + (64  + cl) * 136 + ko);
            aR = __builtin_amdgcn_mfma_f32_16x16x32_bf16(zf[kc], b0, aR, 0, 0, 0);
            aZ = __builtin_amdgcn_mfma_f32_16x16x32_bf16(zf[kc], b1, aZ, 0, 0, 0);
            aN = __builtin_amdgcn_mfma_f32_16x16x32_bf16(zf[kc], b2, aN, 0, 0, 0);
        }
#pragma unroll
        for (int kc = 0; kc < 4; ++kc) {
            const int ko = kc * 32 + hi * 8;
            short8 b0 = *(const short8*)(blds + (96  +      cl) * 136 + ko);
            short8 b1 = *(const short8*)(blds + (96  + 32 + cl) * 136 + ko);
            short8 b2 = *(const short8*)(blds + (96  + 64 + cl) * 136 + ko);
            aR = __builtin_amdgcn_mfma_f32_16x16x32_bf16(hf[kc], b0, aR, 0, 0, 0);
            aZ = __builtin_amdgcn_mfma_f32_16x16x32_bf16(hf[kc], b1, aZ, 0, 0, 0);
            aH = __builtin_amdgcn_mfma_f32_16x16x32_bf16(hf[kc], b2, aH, 0, 0, 0);
        }

        // prefetch next tile's fragments over the gate epilogue
        short8 zfn[4], hfn[4];
        const bool vn = rtn < NT16;
        if (vn) {
            const short8* zr = (const short8*)(Z    + (size_t)(rtn * 16 + li) * HD);
            const short8* hr = (const short8*)(Hold + (size_t)(rtn * 16 + li) * HD);
#pragma unroll
            for (int kc = 0; kc < 4; ++kc) { zfn[kc] = zr[kc * 4 + hi]; hfn[kc] = hr[kc * 4 + hi]; }
        }

#pragma unroll
        for (int r = 0; r < 4; ++r) {
            int gr = rt * 16 + hi * 4 + r;
            float hv = bf2f(((const unsigned short*)Hold)[(size_t)gr * HD + c]);
            float rr = sigf(aR[r] + bR);
            float zz = sigf(aZ[r] + bZg);
            float nn = tanhf_(aN[r] + bIN + rr * (aH[r] + bHN));
            Hnew[(size_t)gr * HD + c] = bf16c((1.f - zz) * nn + zz * hv);
        }

        if (vn) {
#pragma unroll
            for (int kc = 0; kc < 4; ++kc) { zf[kc] = zfn[kc]; hf[kc] = hfn[kc]; }
        }
        rt = rtn;
    }
}

// ---------------------------------------------------------------------------
// policy + in-wave Gumbel sample; Wp1 in LDS; register lp accumulation.
// ---------------------------------------------------------------------------
__global__ __launch_bounds__(256)
void k_polS(const short* __restrict__ H, const short* __restrict__ Wp1T,
            const float* __restrict__ bp1, const float* __restrict__ Wp2,
            const float* __restrict__ gum_t, float* __restrict__ assign,
            float* __restrict__ lp_acc) {
    const int tid  = threadIdx.x;
    const int w    = tid >> 6;
    const int lane = tid & 63;
    const int li   = lane & 15;
    const int hi   = lane >> 4;

    __shared__ short blds[128 * 136];
    for (int c2 = tid; c2 < 2048; c2 += 256) {
        int r = c2 >> 4, off = c2 & 15;
        *(short8*)(blds + r * 136 + off * 8) = *(const short8*)(Wp1T + (size_t)r * 128 + off * 8);
    }
    __syncthreads();

    float bv[8], wpv[8];
#pragma unroll
    for (int t = 0; t < 8; ++t) { bv[t] = bp1[t * 16 + li]; wpv[t] = Wp2[t * 16 + li]; }

    float lpSum = 0.f;
    const int stride = gridDim.x * 4;
    for (int rt = blockIdx.x * 4 + w; rt < NT16; rt += stride) {
        const short8* arow = (const short8*)(H + (size_t)(rt * 16 + li) * HD);
        short8 af[4];
#pragma unroll
        for (int kc = 0; kc < 4; ++kc) af[kc] = arow[kc * 4 + hi];

        f32x4 acc[8];
#pragma unroll
        for (int t = 0; t < 8; ++t) acc[t] = (f32x4){0.f, 0.f, 0.f, 0.f};
#pragma unroll
        for (int kc = 0; kc < 4; ++kc)
#pragma unroll
            for (int t = 0; t < 8; ++t) {
                short8 bf = *(const short8*)(blds + (t * 16 + li) * 136 + kc * 32 + hi * 8);
                acc[t] = __builtin_amdgcn_mfma_f32_16x16x32_bf16(af[kc], bf, acc[t], 0, 0, 0);
            }

        float lg[4];
#pragma unroll
        for (int r = 0; r < 4; ++r) {
            float p = 0.f;
#pragma unroll
            for (int t = 0; t < 8; ++t) p = fmaf(fmaxf(acc[t][r] + bv[t], 0.f), wpv[t], p);
            p += __shfl_xor(p, 1);
            p += __shfl_xor(p, 2);
            p += __shfl_xor(p, 4);
            p += __shfl_xor(p, 8);
            lg[r] = p;
        }

        float bt = -1e30f, bl = 0.f; int bd = 0;
#pragma unroll
        for (int r = 0; r < 4; ++r) {
            float tv = lg[r] + gum_t[rt * 16 + hi * 4 + r];
            int d = (hi & 1) * 4 + r;
            if (tv > bt) { bt = tv; bl = lg[r]; bd = d; }
        }
        float ot = __shfl_xor(bt, 16);
        float ol = __shfl_xor(bl, 16);
        int   od = __shfl_xor(bd, 16);
        if (ot > bt || (ot == bt && od < bd)) { bt = ot; bl = ol; bd = od; }

        float mx = fmaxf(fmaxf(lg[0], lg[1]), fmaxf(lg[2], lg[3]));
        mx = fmaxf(mx, __shfl_xor(mx, 16));
        float se = __expf(lg[0] - mx) + __expf(lg[1] - mx) +
                   __expf(lg[2] - mx) + __expf(lg[3] - mx);
        se += __shfl_xor(se, 16);

        if (li == 0) {
#pragma unroll
            for (int r = 0; r < 4; ++r)
                assign[rt * 16 + hi * 4 + r] = ((hi & 1) * 4 + r == bd) ? 1.f : 0.f;
            if ((hi & 1) == 0) lpSum += bl - mx - __logf(se);
        }
    }

    __shared__ float sred[256];
    sred[tid] = lpSum;
    __syncthreads();
    for (int o = 128; o > 0; o >>= 1) {
        if (tid < o) sred[tid] += sred[tid + o];
        __syncthreads();
    }
    if (tid == 0) atomicAdd(lp_acc, sred[0]);
}

// ---------------------------------------------------------------------------
extern "C" void kernel_launch(void* const* d_in, const int* in_sizes, int n_in,
                              void* d_out, int out_size, void* d_ws, size_t ws_size,
                              hipStream_t stream) {
    const float* h_init = (const float*)d_in[0];
    const float* W1  = (const float*)d_in[1];
    const float* b1  = (const float*)d_in[2];
    const float* W2  = (const float*)d_in[3];
    const float* Wx  = (const float*)d_in[4];
    const float* bx  = (const float*)d_in[5];
    const float* Wc  = (const float*)d_in[6];
    const float* bc  = (const float*)d_in[7];
    const float* Wv  = (const float*)d_in[8];
    const float* bv  = (const float*)d_in[9];
    const float* Wi  = (const float*)d_in[10];
    const float* Wh  = (const float*)d_in[11];
    const float* bi  = (const float*)d_in[12];
    const float* bh  = (const float*)d_in[13];
    const float* Wp1 = (const float*)d_in[14];
    const float* bp1 = (const float*)d_in[15];
    const float* Wp2 = (const float*)d_in[16];
    const float* gum = (const float*)d_in[17];
    const int* val_idx = (const int*)d_in[18];
    float* out = (float*)d_out;

    const int S = (out_size - 1) / 2;

    const size_t VH = (size_t)NVAL * HD;
    short* hbA   = (short*)d_ws;                      // VH bf16
    short* hbB   = hbA + VH;
    short* tA    = hbB + VH;                          // z
    short* uV    = tA + VH;                           // u_val
    short* yV    = uV + VH;                           // y_val
    short* s_cst = yV + VH;                           // NCST*HD
    short* r2c   = s_cst + (size_t)NCST * HD;         // NCST*HD (L2-resident)
    short* W1T  = r2c + (size_t)NCST * HD;
    short* W2cT = W1T  + 16384;
    short* WxT  = W2cT + 16384;
    short* Wp1T = WxT  + 16384;
    short* WcBP = Wp1T + 16384;                       // permuted WcBot
    short* WvT  = WcBP + 16384;                       // 128 x 256
    short* WiT  = WvT  + 32768;
    short* WhT  = WiT  + 49152;
    float* assign = (float*)(WhT + 49152);            // NVAL
    float* lp_acc = assign + NVAL;                    // 8
    int*   sat    = (int*)(lp_acc + 8);               // 8
    float* best   = (float*)(sat + 8);                // 8
    int*   deg    = (int*)(best + 8);                 // NVAL
    int*   off    = deg + NVAL;                       // NVAL+1
    int*   cursor = off + NVAL + 1;                   // NVAL
    int*   inv    = cursor + NVAL;                    // NEDGE
    int*   bsum   = inv + NEDGE;                      // 625
    int*   boff   = bsum + 625;                       // 626

    const size_t needed = (size_t)((char*)(boff + 626) - (char*)d_ws);
    if (ws_size < needed) {
        k_report<<<1, 1, 0, stream>>>(out, (float)ws_size);
        return;
    }

    // ---- one-time: weights + folds + CSR inversion ----
    WDs ds;
    ds.d[0] = { W1,  W1T,  128, 128, 16384 };
    ds.d[1] = { Wx,  WxT,  128, 128, 16384 };
    ds.d[2] = { Wp1, Wp1T, 128, 128, 16384 };
    ds.d[3] = { Wv,  WvT,  256, 128, 32768 };
    ds.d[4] = { Wi,  WiT,  128, 384, 49152 };
    ds.d[5] = { Wh,  WhT,  128, 384, 49152 };
    k_wconv6<<<dim3(192, 6), dim3(256), 0, stream>>>(ds);
    k_w2c <<<dim3(64), dim3(256), 0, stream>>>(W2, Wc, W2cT);
    k_wcbp<<<dim3(64), dim3(256), 0, stream>>>(Wc, WcBP);

    (void)hipMemsetAsync(lp_acc, 0, 24 * sizeof(float), stream);
    (void)hipMemsetAsync(deg, 0, (size_t)NVAL * sizeof(int), stream);
    k_hist <<<dim3(625), dim3(256), 0, stream>>>(val_idx, deg);
    k_scan1<<<dim3(625), dim3(256), 0, stream>>>(deg, bsum);
    k_scan2<<<1, 1, 0, stream>>>(bsum, boff, 625);
    k_scan3<<<dim3(625), dim3(256), 0, stream>>>(deg, boff, off, cursor);
    k_place<<<dim3(625), dim3(256), 0, stream>>>(val_idx, cursor, inv);

    const dim3 B256(256);
    const dim3 gA(1280);       // K=128 GEMMs over NVAL
    const dim3 gW(320);        // small GEMM over NCST
    const dim3 gXU(512);       // fused x_val->uV
    const dim3 gB(2048);       // Z8 (col-half = bid&1)
    const dim3 gG(512);        // gruN: 4 col groups (serial) x 128 row blocks
    const dim3 gS(2048);       // gather
    const dim3 gVar((NVAR + 255) / 256);
    const float* w1r128 = W1 + (size_t)128 * HD;

    k_init_hb<<<dim3(NVAL * HD / 256), B256, 0, stream>>>(hbA, h_init);
    k_sample0<<<gVar, B256, 0, stream>>>(gum, assign, lp_acc);
    k_unsat<<<gVar, B256, 0, stream>>>(assign, val_idx, sat);
    k_finalize<<<1, 1, 0, stream>>>(lp_acc, sat, best, out, 0, S, 0);

    for (int s = 0; s < S; ++s) {
        const int t = s + 1;
        const short* hcur = (s & 1) ? hbB : hbA;
        short*       hnxt = (s & 1) ? hbA : hbB;
        // 1. s_cst = sum8(relu([h[val_idx] | bit] @ W1 + b1))
        k_gemmA<AM_GATHER, true, true, EPI_RCST><<<gA, B256, 0, stream>>>(
            hcur, val_idx, assign, w1r128, W1T, b1, nullptr, s_cst, NVAL);
        // 2. r2c = s_cst @ (W2 @ WcTop)
        k_gemmA<AM_DIRECT, false, false, EPI_STORE><<<gW, B256, 0, stream>>>(
            s_cst, nullptr, nullptr, nullptr, W2cT, nullptr, r2c, nullptr, NCST);
        // 3. uV = relu(h @ Wx + bx) @ WcBot   (fused)
        k_gemmXU<<<gXU, B256, 0, stream>>>(hcur, WxT, WcBP, bx, uV);
        // 4. yV = wave-uniform CSR gather of relu(r2c + uV + bc)
        k_gather<<<gS, B256, 0, stream>>>(r2c, uV, off, inv, bc, yV);
        // 5+6. tA = z = relu([yV | mean8(yV)] @ Wv + bv)
        k_gemmZ8<<<gB, B256, 0, stream>>>(yV, WvT, bv, tA);
        // 7. hnxt = GRU(z, hcur)   (R=4, 512-thr row-sharing)
        k_gruN<<<gG, dim3(512), 0, stream>>>(tA, hcur, hnxt, WiT, WhT, bi, bh);
        // 8+9a. policy + in-wave sample -> assign, lp
        k_polS<<<gA, B256, 0, stream>>>(hnxt, Wp1T, bp1, Wp2,
                                        gum + (size_t)t * NVAL, assign, lp_acc + t);
        // 9b. unsat + outputs
        k_unsat<<<gVar, B256, 0, stream>>>(assign, val_idx, sat + t);
        k_finalize<<<1, 1, 0, stream>>>(lp_acc + t, sat + t, best, out, s, S, 1);
    }
}

// Round 16
// 1151.990 us; speedup vs baseline: 1.1139x; 1.0492x over previous
//
#include <hip/hip_runtime.h>
#include <math.h>

#define NVAR  20000
#define NVAL  160000
#define NCST  20000
#define NEDGE 160000
#define HD    128
#define NT16  10000    // NVAL/16 row-tiles

typedef __attribute__((ext_vector_type(8))) short  short8;   // 8 bf16 (4 VGPRs)
typedef __attribute__((ext_vector_type(4))) float  f32x4;    // MFMA accumulator
typedef __attribute__((ext_vector_type(4))) float  floatx4;

// fast gates (2% tolerance)
static __device__ __forceinline__ float sigf(float x) {
    return __fdividef(1.0f, 1.0f + __expf(-x));
}
static __device__ __forceinline__ float tanhf_(float x) {
    return 1.0f - __fdividef(2.0f, 1.0f + __expf(2.0f * x));
}

static __device__ __forceinline__ short bf16c(float f) {   // RNE f32->bf16
    unsigned u = __float_as_uint(f);
    u += 0x7fffu + ((u >> 16) & 1u);
    return (short)(u >> 16);
}
static __device__ __forceinline__ float bf2f(unsigned short b) {
    return __uint_as_float(((unsigned)b) << 16);
}
static __device__ __forceinline__ short8 pack8(floatx4 a, floatx4 b) {
    short8 r;
    r[0] = bf16c(a[0]); r[1] = bf16c(a[1]); r[2] = bf16c(a[2]); r[3] = bf16c(a[3]);
    r[4] = bf16c(b[0]); r[5] = bf16c(b[1]); r[6] = bf16c(b[2]); r[7] = bf16c(b[3]);
    return r;
}

// ---------------------------------------------------------------------------
// one-time weight convert+transpose: W[K][N] f32 -> WT[N][K] bf16
// ---------------------------------------------------------------------------
struct WD  { const float* W; short* WT; int K; int N; int total; };
struct WDs { WD d[6]; };

__global__ __launch_bounds__(256) void k_wconv6(WDs ds) {
    WD d = ds.d[blockIdx.y];
    int i = blockIdx.x * 256 + threadIdx.x;
    if (i >= d.total) return;
    int n = i / d.K, k = i - n * d.K;
    d.WT[i] = bf16c(d.W[(size_t)k * d.N + n]);
}

// one-time: W2cT[n][k] = (W2 @ Wc_top)[k][n] in f32, stored bf16 transposed
__global__ __launch_bounds__(256) void k_w2c(const float* __restrict__ W2,
                                             const float* __restrict__ Wc,
                                             short* __restrict__ W2cT) {
    int i = blockIdx.x * 256 + threadIdx.x;   // 16384
    int n = i >> 7, k = i & 127;
    float s = 0.f;
    for (int m = 0; m < 128; ++m) s += W2[k * 128 + m] * Wc[m * 128 + n];
    W2cT[n * 128 + k] = bf16c(s);
}

// one-time: WcBot permuted for the fused XU kernel's custom k-bijection:
// slot s = kc*32 + hi*8 + j  holds  WcBot[k(hi,kc,j)][n2],
// k(hi,kc,j) = (kc*2 + (j>>2))*16 + hi*4 + (j&3).
__global__ __launch_bounds__(256) void k_wcbp(const float* __restrict__ Wc,
                                              short* __restrict__ WcBP) {
    int i = blockIdx.x * 256 + threadIdx.x;   // 16384
    int n2 = i >> 7, s = i & 127;
    int kc = s >> 5, rem = s & 31, hi2 = rem >> 3, j = rem & 7;
    int k = (kc * 2 + (j >> 2)) * 16 + hi2 * 4 + (j & 3);
    WcBP[n2 * 128 + s] = bf16c(Wc[(size_t)(128 + k) * 128 + n2]);
}

// ---------------------------------------------------------------------------
// CSR inversion of val_idx (one-time); inv stores CONSTRAINT id (e>>3)
// ---------------------------------------------------------------------------
__global__ __launch_bounds__(256) void k_hist(const int* __restrict__ val_idx,
                                              int* __restrict__ deg) {
    int e = blockIdx.x * 256 + threadIdx.x;
    if (e < NEDGE) atomicAdd(&deg[val_idx[e]], 1);
}
__global__ __launch_bounds__(256) void k_scan1(const int* __restrict__ deg,
                                               int* __restrict__ bsum) {
    __shared__ int s[256];
    int i = blockIdx.x * 256 + threadIdx.x;
    s[threadIdx.x] = deg[i];
    __syncthreads();
    for (int o = 128; o > 0; o >>= 1) {
        if (threadIdx.x < o) s[threadIdx.x] += s[threadIdx.x + o];
        __syncthreads();
    }
    if (threadIdx.x == 0) bsum[blockIdx.x] = s[0];
}
__global__ void k_scan2(const int* __restrict__ bsum, int* __restrict__ boff, int nb) {
    if (threadIdx.x == 0 && blockIdx.x == 0) {
        int acc = 0;
        for (int b = 0; b < nb; ++b) { boff[b] = acc; acc += bsum[b]; }
        boff[nb] = acc;
    }
}
__global__ __launch_bounds__(256) void k_scan3(const int* __restrict__ deg,
                                               const int* __restrict__ boff,
                                               int* __restrict__ off,
                                               int* __restrict__ cursor) {
    __shared__ int s[256];
    int i = blockIdx.x * 256 + threadIdx.x;
    int d = deg[i];
    s[threadIdx.x] = d;
    __syncthreads();
    for (int o = 1; o < 256; o <<= 1) {
        int v = s[threadIdx.x];
        if (threadIdx.x >= o) v += s[threadIdx.x - o];
        __syncthreads();
        s[threadIdx.x] = v;
        __syncthreads();
    }
    int excl = s[threadIdx.x] - d + boff[blockIdx.x];
    off[i] = excl;
    cursor[i] = excl;
    if (i == NVAL - 1) off[NVAL] = NEDGE;
}
__global__ __launch_bounds__(256) void k_place(const int* __restrict__ val_idx,
                                               int* __restrict__ cursor,
                                               int* __restrict__ inv) {
    int e = blockIdx.x * 256 + threadIdx.x;
    if (e < NEDGE) {
        int p = atomicAdd(&cursor[val_idx[e]], 1);
        inv[p] = e >> 3;                       // constraint id directly
    }
}

// ---------------------------------------------------------------------------
// small kernels
// ---------------------------------------------------------------------------
__global__ __launch_bounds__(256) void k_init_hb(short* __restrict__ h,
                                                 const float* __restrict__ hinit) {
    size_t i = (size_t)blockIdx.x * 256 + threadIdx.x;
    h[i] = bf16c(hinit[i & (HD - 1)]);
}

__global__ __launch_bounds__(256) void k_sample0(const float* __restrict__ g,
                                                 float* __restrict__ assign,
                                                 float* __restrict__ lp_accum) {
    int v = blockIdx.x * 256 + threadIdx.x;
    float lp = 0.f;
    if (v < NVAR) {
        int choice = 0;
        float bestv = -1e30f;
#pragma unroll
        for (int d = 0; d < 8; ++d) {
            float t = g[v * 8 + d];
            if (t > bestv) { bestv = t; choice = d; }
        }
        lp = -__logf(8.0f);
#pragma unroll
        for (int d = 0; d < 8; ++d) assign[v * 8 + d] = (d == choice) ? 1.f : 0.f;
    }
    __shared__ float sred[256];
    sred[threadIdx.x] = lp;
    __syncthreads();
    for (int o = 128; o > 0; o >>= 1) {
        if (threadIdx.x < o) sred[threadIdx.x] += sred[threadIdx.x + o];
        __syncthreads();
    }
    if (threadIdx.x == 0) atomicAdd(lp_accum, sred[0]);
}

__global__ __launch_bounds__(256) void k_unsat(const float* __restrict__ assign,
                                               const int* __restrict__ val_idx,
                                               int* __restrict__ sat_accum) {
    int c = blockIdx.x * 256 + threadIdx.x;
    int sat = 0;
    if (c < NCST) {
#pragma unroll
        for (int j = 0; j < 8; ++j)
            if (assign[val_idx[c * 8 + j]] > 0.5f) sat = 1;
    }
    __shared__ int sred[256];
    sred[threadIdx.x] = sat;
    __syncthreads();
    for (int o = 128; o > 0; o >>= 1) {
        if (threadIdx.x < o) sred[threadIdx.x] += sred[threadIdx.x + o];
        __syncthreads();
    }
    if (threadIdx.x == 0) atomicAdd(sat_accum, sred[0]);
}

__global__ void k_finalize(const float* __restrict__ lp, const int* __restrict__ sat,
                           float* __restrict__ best, float* __restrict__ out,
                           int s, int S, int mode) {
    float nu = (float)NCST - (float)(*sat);
    if (mode == 0) {
        *best = nu;
    } else {
        out[s] = *lp;
        out[S + s] = nu;
        float b = *best;
        if (nu < b) b = nu;
        *best = b;
        if (s == S - 1) out[2 * S] = b;
    }
}

__global__ void k_report(float* out, float v) {
    for (int i = 0; i < 9; ++i) out[i] = v;
}

// ---------------------------------------------------------------------------
// LDS-B MFMA GEMM, K=128, 128 cols/wave (steps 1, r2c)
// ---------------------------------------------------------------------------
static constexpr int AM_DIRECT = 1, AM_GATHER = 2;
static constexpr int EPI_STORE = 0, EPI_RCST = 1;

template <int A0M, bool BIT, bool RELU, int EPI>
__global__ __launch_bounds__(256)
void k_gemmA(const short* __restrict__ A, const int* __restrict__ aidx,
             const float* __restrict__ abit, const float* __restrict__ w1r128,
             const short* __restrict__ WT, const float* __restrict__ bias0,
             short* __restrict__ outBF, short* __restrict__ rcstOut,
             int nrows) {
    const int tid  = threadIdx.x;
    const int w    = tid >> 6;
    const int lane = tid & 63;
    const int li   = lane & 15;
    const int hi   = lane >> 4;

    __shared__ short blds[128 * 136];
    for (int c2 = tid; c2 < 2048; c2 += 256) {
        int r = c2 >> 4, off = c2 & 15;
        *(short8*)(blds + r * 136 + off * 8) = *(const short8*)(WT + (size_t)r * 128 + off * 8);
    }
    __syncthreads();

    float bv[8];
#pragma unroll
    for (int t = 0; t < 8; ++t) bv[t] = bias0 ? bias0[t * 16 + li] : 0.f;
    float wv[8];
    if constexpr (BIT) {
#pragma unroll
        for (int t = 0; t < 8; ++t) wv[t] = w1r128[t * 16 + li];
    }

    const int nt = nrows >> 4;
    const int stride = gridDim.x * 4;
    for (int rt = blockIdx.x * 4 + w; rt < nt; rt += stride) {
        const int ar = rt * 16 + li;
        int ia = ar;
        if constexpr (A0M == AM_GATHER) ia = aidx[ar];
        const short8* arow = (const short8*)(A + (size_t)ia * HD);

        short8 af[4];
#pragma unroll
        for (int kc = 0; kc < 4; ++kc) af[kc] = arow[kc * 4 + hi];

        f32x4 acc[8];
#pragma unroll
        for (int t = 0; t < 8; ++t) acc[t] = (f32x4){0.f, 0.f, 0.f, 0.f};
#pragma unroll
        for (int kc = 0; kc < 4; ++kc)
#pragma unroll
            for (int t = 0; t < 8; ++t) {
                short8 bf = *(const short8*)(blds + (t * 16 + li) * 136 + kc * 32 + hi * 8);
                acc[t] = __builtin_amdgcn_mfma_f32_16x16x32_bf16(af[kc], bf, acc[t], 0, 0, 0);
            }

        if constexpr (BIT) {
#pragma unroll
            for (int r = 0; r < 4; ++r) {
                int gr = rt * 16 + hi * 4 + r;
                float bitv = abit[aidx[gr]];
#pragma unroll
                for (int t = 0; t < 8; ++t) acc[t][r] += bitv * wv[t];
            }
        }
#pragma unroll
        for (int t = 0; t < 8; ++t)
#pragma unroll
            for (int r = 0; r < 4; ++r) {
                acc[t][r] += bv[t];
                if constexpr (RELU) acc[t][r] = fmaxf(acc[t][r], 0.f);
            }

        if constexpr (EPI == EPI_STORE) {
#pragma unroll
            for (int r = 0; r < 4; ++r) {
                int gr = rt * 16 + hi * 4 + r;
                short* o = outBF + (size_t)gr * HD + li;
#pragma unroll
                for (int t = 0; t < 8; ++t) o[t * 16] = bf16c(acc[t][r]);
            }
        } else {  // EPI_RCST: sum groups of 8 rows
#pragma unroll
            for (int t = 0; t < 8; ++t) {
                float s = acc[t][0] + acc[t][1] + acc[t][2] + acc[t][3];
                s += __shfl_xor(s, 16);
                if (hi == 0)      rcstOut[(size_t)(rt * 2) * HD + t * 16 + li]     = bf16c(s);
                else if (hi == 2) rcstOut[(size_t)(rt * 2 + 1) * HD + t * 16 + li] = bf16c(s);
            }
        }
    }
}

// ---------------------------------------------------------------------------
// fused steps 3a+3b: uV = (relu(h @ Wx + bx)) @ WcBot (operand-swap pass 1 +
// custom k-bijection pass 2; WcBP pre-permuted; exact by k-map invariance)
// ---------------------------------------------------------------------------
__global__ __launch_bounds__(256)
void k_gemmXU(const short* __restrict__ H, const short* __restrict__ WxT,
              const short* __restrict__ WcBP, const float* __restrict__ bx,
              short* __restrict__ uV) {
    const int tid  = threadIdx.x;
    const int w    = tid >> 6;
    const int lane = tid & 63;
    const int li   = lane & 15;
    const int hi   = lane >> 4;

    __shared__ short wx[128 * 136];
    __shared__ short wc[128 * 136];
    for (int c2 = tid; c2 < 2048; c2 += 256) {
        int r = c2 >> 4, off = c2 & 15;
        *(short8*)(wx + r * 136 + off * 8) = *(const short8*)(WxT  + (size_t)r * 128 + off * 8);
        *(short8*)(wc + r * 136 + off * 8) = *(const short8*)(WcBP + (size_t)r * 128 + off * 8);
    }
    __syncthreads();

    float bx32[8][4];
#pragma unroll
    for (int t = 0; t < 8; ++t)
#pragma unroll
        for (int r = 0; r < 4; ++r) bx32[t][r] = bx[t * 16 + hi * 4 + r];

    const int stride = gridDim.x * 4;
    for (int rt = blockIdx.x * 4 + w; rt < NT16; rt += stride) {
        const short8* arow = (const short8*)(H + (size_t)(rt * 16 + li) * HD);
        short8 af[4];
#pragma unroll
        for (int kc = 0; kc < 4; ++kc) af[kc] = arow[kc * 4 + hi];

        f32x4 a1[8];
#pragma unroll
        for (int t = 0; t < 8; ++t) a1[t] = (f32x4){0.f, 0.f, 0.f, 0.f};
#pragma unroll
        for (int kc = 0; kc < 4; ++kc)
#pragma unroll
            for (int t = 0; t < 8; ++t) {
                short8 wf = *(const short8*)(wx + (t * 16 + li) * 136 + kc * 32 + hi * 8);
                a1[t] = __builtin_amdgcn_mfma_f32_16x16x32_bf16(wf, af[kc], a1[t], 0, 0, 0);
            }

        floatx4 xv[8];
#pragma unroll
        for (int t = 0; t < 8; ++t)
#pragma unroll
            for (int r = 0; r < 4; ++r)
                xv[t][r] = fmaxf(a1[t][r] + bx32[t][r], 0.f);

        short8 af2[4];
#pragma unroll
        for (int kc = 0; kc < 4; ++kc) af2[kc] = pack8(xv[2 * kc], xv[2 * kc + 1]);

        f32x4 a2[8];
#pragma unroll
        for (int t = 0; t < 8; ++t) a2[t] = (f32x4){0.f, 0.f, 0.f, 0.f};
#pragma unroll
        for (int kc = 0; kc < 4; ++kc)
#pragma unroll
            for (int t = 0; t < 8; ++t) {
                short8 bf = *(const short8*)(wc + (t * 16 + li) * 136 + kc * 32 + hi * 8);
                a2[t] = __builtin_amdgcn_mfma_f32_16x16x32_bf16(af2[kc], bf, a2[t], 0, 0, 0);
            }

#pragma unroll
        for (int r = 0; r < 4; ++r) {
            int gr = rt * 16 + hi * 4 + r;
            short* o = uV + (size_t)gr * HD + li;
#pragma unroll
            for (int t = 0; t < 8; ++t) o[t * 16] = bf16c(a2[t][r]);
        }
    }
}

// ---------------------------------------------------------------------------
// step 4: wave-per-value CSR gather (deg wave-uniform, no divergence)
// ---------------------------------------------------------------------------
__global__ __launch_bounds__(256)
void k_gather(const short* __restrict__ r2c, const short* __restrict__ uV,
              const int* __restrict__ off, const int* __restrict__ inv,
              const float* __restrict__ bcv, short* __restrict__ yV) {
    const int w    = threadIdx.x >> 6;
    const int lane = threadIdx.x & 63;
    const int c0   = lane * 2;

    const float b0 = bcv[c0], b1 = bcv[c0 + 1];

    for (int v = blockIdx.x * 4 + w; v < NVAL; v += gridDim.x * 4) {
        const int e0 = off[v], e1 = off[v + 1];
        unsigned uu = *(const unsigned*)(uV + (size_t)v * HD + c0);
        const float u0 = bf2f((unsigned short)(uu & 0xffffu)) + b0;
        const float u1 = bf2f((unsigned short)(uu >> 16)) + b1;
        float a0 = 0.f, a1 = 0.f;
        for (int e = e0; e < e1; ++e) {
            const int cst = inv[e];
            unsigned rv = *(const unsigned*)(r2c + (size_t)cst * HD + c0);
            a0 += fmaxf(bf2f((unsigned short)(rv & 0xffffu)) + u0, 0.f);
            a1 += fmaxf(bf2f((unsigned short)(rv >> 16)) + u1, 0.f);
        }
        unsigned o = (unsigned)(unsigned short)bf16c(a0) |
                     ((unsigned)(unsigned short)bf16c(a1) << 16);
        *(unsigned*)(yV + (size_t)v * HD + c0) = o;
    }
}

// ---------------------------------------------------------------------------
// steps 5+6: z = relu([yV | mean8(yV)] @ Wv + bv); B (col-half) in LDS.
// ---------------------------------------------------------------------------
__global__ __launch_bounds__(256)
void k_gemmZ8(const short* __restrict__ yV, const short* __restrict__ WvT,
              const float* __restrict__ bvv, short* __restrict__ outT) {
    const int tid  = threadIdx.x;
    const int w    = tid >> 6;
    const int lane = tid & 63;
    const int li   = lane & 15;
    const int hi   = lane >> 4;
    const int ch   = blockIdx.x & 1;
    const int rba  = blockIdx.x >> 1;

    __shared__ short blds[64 * 264];
    for (int c2 = tid; c2 < 2048; c2 += 256) {
        int r = c2 >> 5, off = c2 & 31;
        *(short8*)(blds + r * 264 + off * 8) =
            *(const short8*)(WvT + (size_t)(ch * 64 + r) * 256 + off * 8);
    }
    __syncthreads();

    float bv[4];
#pragma unroll
    for (int t = 0; t < 4; ++t) bv[t] = bvv[ch * 64 + t * 16 + li];

    for (int rt = rba * 4 + w; rt < NT16; rt += 4096) {
        const int v = rt * 16 + li;
        const short8* yr = (const short8*)(yV + (size_t)v * HD);

        short8 af[8];
        floatx4 m[8];
#pragma unroll
        for (int kc = 0; kc < 4; ++kc) {
            short8 yv = yr[kc * 4 + hi];
            af[kc] = yv;
#pragma unroll
            for (int j = 0; j < 4; ++j) {
                m[2 * kc][j]     = bf2f((unsigned short)yv[j]);
                m[2 * kc + 1][j] = bf2f((unsigned short)yv[4 + j]);
            }
        }
#pragma unroll
        for (int q = 0; q < 8; ++q)
#pragma unroll
            for (int e2 = 0; e2 < 4; ++e2) {
                m[q][e2] += __shfl_xor(m[q][e2], 1);
                m[q][e2] += __shfl_xor(m[q][e2], 2);
                m[q][e2] += __shfl_xor(m[q][e2], 4);
                m[q][e2] *= 0.125f;
            }
#pragma unroll
        for (int kc = 0; kc < 4; ++kc) af[4 + kc] = pack8(m[2 * kc], m[2 * kc + 1]);

        f32x4 acc[4];
#pragma unroll
        for (int t = 0; t < 4; ++t) acc[t] = (f32x4){0.f, 0.f, 0.f, 0.f};
#pragma unroll
        for (int kc = 0; kc < 8; ++kc)
#pragma unroll
            for (int t = 0; t < 4; ++t) {
                short8 bf = *(const short8*)(blds + (t * 16 + li) * 264 + kc * 32 + hi * 8);
                acc[t] = __builtin_amdgcn_mfma_f32_16x16x32_bf16(af[kc], bf, acc[t], 0, 0, 0);
            }

#pragma unroll
        for (int r = 0; r < 4; ++r) {
            int gr = rt * 16 + hi * 4 + r;
            short* o = outT + (size_t)gr * HD + ch * 64 + li;
#pragma unroll
            for (int t = 0; t < 4; ++t)
                o[t * 16] = bf16c(fmaxf(acc[t][r] + bv[t], 0.f));
        }
    }
}

// ---------------------------------------------------------------------------
// GRU k_gruN (v2): R=4 traffic + full prefetch + 3 blocks/CU.
// 512 thr = 8 waves sharing one 52KB slab (32 cols of Wi/Wh); waves 0-3 own
// the low 16-col sub-tile, 4-7 the high one.  PREFETCH now includes the
// epilogue's Hold[gr][c] re-read (hv) — previously an exposed ~500cyc
// dependent load after the MFMAs.  Grid 768 = 3 blocks/CU (156KB LDS).
// ---------------------------------------------------------------------------
#define GRU_NRB 192   // row-groups; grid = 4 * GRU_NRB
__global__ __launch_bounds__(512)
void k_gruN(const short* __restrict__ Z, const short* __restrict__ Hold,
            short* __restrict__ Hnew,
            const short* __restrict__ WiT, const short* __restrict__ WhT,
            const float* __restrict__ bi, const float* __restrict__ bh) {
    const int tid  = threadIdx.x;
    const int w    = tid >> 6;
    const int cu   = w >> 2;              // 0/1: 16-col sub-tile
    const int wr   = w & 3;               // row wave
    const int lane = tid & 63;
    const int li   = lane & 15;
    const int hi   = lane >> 4;
    const int g    = blockIdx.x / GRU_NRB;    // 0..3 col group (32 cols), serial
    const int rba  = blockIdx.x % GRU_NRB;

    // rows 0..95: Wi (3 slabs x 32 cols); rows 96..191: Wh
    __shared__ short blds[192 * 136];
    for (int c2 = tid; c2 < 3072; c2 += 512) {
        int r = c2 >> 4, off = c2 & 15;
        int r2 = (r < 96) ? r : r - 96;
        int sl = r2 >> 5, l = r2 & 31;
        const short* src = ((r < 96) ? WiT : WhT) + (size_t)(sl * 128 + g * 32 + l) * 128 + off * 8;
        *(short8*)(blds + r * 136 + off * 8) = *(const short8*)src;
    }
    __syncthreads();

    const int cl = cu * 16 + li;          // col within the 32-col slab
    const int c  = g * 32 + cl;
    const float bR  = bi[c] + bh[c];
    const float bZg = bi[128 + c] + bh[128 + c];
    const float bIN = bi[256 + c];
    const float bHN = bh[256 + c];

    const unsigned short* HoldU = (const unsigned short*)Hold;
    const int stride = GRU_NRB * 4;       // 768
    int rt = rba * 4 + wr;
    short8 zf[4], hf[4];
    unsigned short hv[4];
    if (rt < NT16) {
        const short8* zr = (const short8*)(Z    + (size_t)(rt * 16 + li) * HD);
        const short8* hr = (const short8*)(Hold + (size_t)(rt * 16 + li) * HD);
#pragma unroll
        for (int kc = 0; kc < 4; ++kc) { zf[kc] = zr[kc * 4 + hi]; hf[kc] = hr[kc * 4 + hi]; }
#pragma unroll
        for (int r = 0; r < 4; ++r)
            hv[r] = HoldU[(size_t)(rt * 16 + hi * 4 + r) * HD + c];
    }
    while (rt < NT16) {
        const int rtn = rt + stride;

        f32x4 aR = {0.f,0.f,0.f,0.f}, aZ = {0.f,0.f,0.f,0.f};
        f32x4 aN = {0.f,0.f,0.f,0.f}, aH = {0.f,0.f,0.f,0.f};
#pragma unroll
        for (int kc = 0; kc < 4; ++kc) {
            const int ko = kc * 32 + hi * 8;
            short8 b0 = *(const short8*)(blds + (      cl) * 136 + ko);
            short8 b1 = *(const short8*)(blds + (32  + cl) * 136 + ko);
            short8 b2 = *(const short8*)(blds + (64  + cl) * 136 + ko);
            aR = __builtin_amdgcn_mfma_f32_16x16x32_bf16(zf[kc], b0, aR, 0, 0, 0);
            aZ = __builtin_amdgcn_mfma_f32_16x16x32_bf16(zf[kc], b1, aZ, 0, 0, 0);
            aN = __builtin_amdgcn_mfma_f32_16x16x32_bf16(zf[kc], b2, aN, 0, 0, 0);
        }
#pragma unroll
        for (int kc = 0; kc < 4; ++kc) {
            const int ko = kc * 32 + hi * 8;
            short8 b0 = *(const short8*)(blds + (96  +      cl) * 136 + ko);
            short8 b1 = *(const short8*)(blds + (96  + 32 + cl) * 136 + ko);
            short8 b2 = *(const short8*)(blds + (96  + 64 + cl) * 136 + ko);
            aR = __builtin_amdgcn_mfma_f32_16x16x32_bf16(hf[kc], b0, aR, 0, 0, 0);
            aZ = __builtin_amdgcn_mfma_f32_16x16x32_bf16(hf[kc], b1, aZ, 0, 0, 0);
            aH = __builtin_amdgcn_mfma_f32_16x16x32_bf16(hf[kc], b2, aH, 0, 0, 0);
        }

        // prefetch next tile's fragments AND hv over the gate epilogue
        short8 zfn[4], hfn[4];
        unsigned short hvn[4];
        const bool vn = rtn < NT16;
        if (vn) {
            const short8* zr = (const short8*)(Z    + (size_t)(rtn * 16 + li) * HD);
            const short8* hr = (const short8*)(Hold + (size_t)(rtn * 16 + li) * HD);
#pragma unroll
            for (int kc = 0; kc < 4; ++kc) { zfn[kc] = zr[kc * 4 + hi]; hfn[kc] = hr[kc * 4 + hi]; }
#pragma unroll
            for (int r = 0; r < 4; ++r)
                hvn[r] = HoldU[(size_t)(rtn * 16 + hi * 4 + r) * HD + c];
        }

#pragma unroll
        for (int r = 0; r < 4; ++r) {
            int gr = rt * 16 + hi * 4 + r;
            float hvf = bf2f(hv[r]);
            float rr = sigf(aR[r] + bR);
            float zz = sigf(aZ[r] + bZg);
            float nn = tanhf_(aN[r] + bIN + rr * (aH[r] + bHN));
            Hnew[(size_t)gr * HD + c] = bf16c((1.f - zz) * nn + zz * hvf);
        }

        if (vn) {
#pragma unroll
            for (int kc = 0; kc < 4; ++kc) { zf[kc] = zfn[kc]; hf[kc] = hfn[kc]; }
#pragma unroll
            for (int r = 0; r < 4; ++r) hv[r] = hvn[r];
        }
        rt = rtn;
    }
}

// ---------------------------------------------------------------------------
// policy + in-wave Gumbel sample; Wp1 in LDS; register lp accumulation.
// ---------------------------------------------------------------------------
__global__ __launch_bounds__(256)
void k_polS(const short* __restrict__ H, const short* __restrict__ Wp1T,
            const float* __restrict__ bp1, const float* __restrict__ Wp2,
            const float* __restrict__ gum_t, float* __restrict__ assign,
            float* __restrict__ lp_acc) {
    const int tid  = threadIdx.x;
    const int w    = tid >> 6;
    const int lane = tid & 63;
    const int li   = lane & 15;
    const int hi   = lane >> 4;

    __shared__ short blds[128 * 136];
    for (int c2 = tid; c2 < 2048; c2 += 256) {
        int r = c2 >> 4, off = c2 & 15;
        *(short8*)(blds + r * 136 + off * 8) = *(const short8*)(Wp1T + (size_t)r * 128 + off * 8);
    }
    __syncthreads();

    float bv[8], wpv[8];
#pragma unroll
    for (int t = 0; t < 8; ++t) { bv[t] = bp1[t * 16 + li]; wpv[t] = Wp2[t * 16 + li]; }

    float lpSum = 0.f;
    const int stride = gridDim.x * 4;
    for (int rt = blockIdx.x * 4 + w; rt < NT16; rt += stride) {
        const short8* arow = (const short8*)(H + (size_t)(rt * 16 + li) * HD);
        short8 af[4];
#pragma unroll
        for (int kc = 0; kc < 4; ++kc) af[kc] = arow[kc * 4 + hi];

        f32x4 acc[8];
#pragma unroll
        for (int t = 0; t < 8; ++t) acc[t] = (f32x4){0.f, 0.f, 0.f, 0.f};
#pragma unroll
        for (int kc = 0; kc < 4; ++kc)
#pragma unroll
            for (int t = 0; t < 8; ++t) {
                short8 bf = *(const short8*)(blds + (t * 16 + li) * 136 + kc * 32 + hi * 8);
                acc[t] = __builtin_amdgcn_mfma_f32_16x16x32_bf16(af[kc], bf, acc[t], 0, 0, 0);
            }

        float lg[4];
#pragma unroll
        for (int r = 0; r < 4; ++r) {
            float p = 0.f;
#pragma unroll
            for (int t = 0; t < 8; ++t) p = fmaf(fmaxf(acc[t][r] + bv[t], 0.f), wpv[t], p);
            p += __shfl_xor(p, 1);
            p += __shfl_xor(p, 2);
            p += __shfl_xor(p, 4);
            p += __shfl_xor(p, 8);
            lg[r] = p;
        }

        float bt = -1e30f, bl = 0.f; int bd = 0;
#pragma unroll
        for (int r = 0; r < 4; ++r) {
            float tv = lg[r] + gum_t[rt * 16 + hi * 4 + r];
            int d = (hi & 1) * 4 + r;
            if (tv > bt) { bt = tv; bl = lg[r]; bd = d; }
        }
        float ot = __shfl_xor(bt, 16);
        float ol = __shfl_xor(bl, 16);
        int   od = __shfl_xor(bd, 16);
        if (ot > bt || (ot == bt && od < bd)) { bt = ot; bl = ol; bd = od; }

        float mx = fmaxf(fmaxf(lg[0], lg[1]), fmaxf(lg[2], lg[3]));
        mx = fmaxf(mx, __shfl_xor(mx, 16));
        float se = __expf(lg[0] - mx) + __expf(lg[1] - mx) +
                   __expf(lg[2] - mx) + __expf(lg[3] - mx);
        se += __shfl_xor(se, 16);

        if (li == 0) {
#pragma unroll
            for (int r = 0; r < 4; ++r)
                assign[rt * 16 + hi * 4 + r] = ((hi & 1) * 4 + r == bd) ? 1.f : 0.f;
            if ((hi & 1) == 0) lpSum += bl - mx - __logf(se);
        }
    }

    __shared__ float sred[256];
    sred[tid] = lpSum;
    __syncthreads();
    for (int o = 128; o > 0; o >>= 1) {
        if (tid < o) sred[tid] += sred[tid + o];
        __syncthreads();
    }
    if (tid == 0) atomicAdd(lp_acc, sred[0]);
}

// ---------------------------------------------------------------------------
extern "C" void kernel_launch(void* const* d_in, const int* in_sizes, int n_in,
                              void* d_out, int out_size, void* d_ws, size_t ws_size,
                              hipStream_t stream) {
    const float* h_init = (const float*)d_in[0];
    const float* W1  = (const float*)d_in[1];
    const float* b1  = (const float*)d_in[2];
    const float* W2  = (const float*)d_in[3];
    const float* Wx  = (const float*)d_in[4];
    const float* bx  = (const float*)d_in[5];
    const float* Wc  = (const float*)d_in[6];
    const float* bc  = (const float*)d_in[7];
    const float* Wv  = (const float*)d_in[8];
    const float* bv  = (const float*)d_in[9];
    const float* Wi  = (const float*)d_in[10];
    const float* Wh  = (const float*)d_in[11];
    const float* bi  = (const float*)d_in[12];
    const float* bh  = (const float*)d_in[13];
    const float* Wp1 = (const float*)d_in[14];
    const float* bp1 = (const float*)d_in[15];
    const float* Wp2 = (const float*)d_in[16];
    const float* gum = (const float*)d_in[17];
    const int* val_idx = (const int*)d_in[18];
    float* out = (float*)d_out;

    const int S = (out_size - 1) / 2;

    const size_t VH = (size_t)NVAL * HD;
    short* hbA   = (short*)d_ws;                      // VH bf16
    short* hbB   = hbA + VH;
    short* tA    = hbB + VH;                          // z
    short* uV    = tA + VH;                           // u_val
    short* yV    = uV + VH;                           // y_val
    short* s_cst = yV + VH;                           // NCST*HD
    short* r2c   = s_cst + (size_t)NCST * HD;         // NCST*HD (L2-resident)
    short* W1T  = r2c + (size_t)NCST * HD;
    short* W2cT = W1T  + 16384;
    short* WxT  = W2cT + 16384;
    short* Wp1T = WxT  + 16384;
    short* WcBP = Wp1T + 16384;                       // permuted WcBot
    short* WvT  = WcBP + 16384;                       // 128 x 256
    short* WiT  = WvT  + 32768;
    short* WhT  = WiT  + 49152;
    float* assign = (float*)(WhT + 49152);            // NVAL
    float* lp_acc = assign + NVAL;                    // 8
    int*   sat    = (int*)(lp_acc + 8);               // 8
    float* best   = (float*)(sat + 8);                // 8
    int*   deg    = (int*)(best + 8);                 // NVAL
    int*   off    = deg + NVAL;                       // NVAL+1
    int*   cursor = off + NVAL + 1;                   // NVAL
    int*   inv    = cursor + NVAL;                    // NEDGE
    int*   bsum   = inv + NEDGE;                      // 625
    int*   boff   = bsum + 625;                       // 626

    const size_t needed = (size_t)((char*)(boff + 626) - (char*)d_ws);
    if (ws_size < needed) {
        k_report<<<1, 1, 0, stream>>>(out, (float)ws_size);
        return;
    }

    // ---- one-time: weights + folds + CSR inversion ----
    WDs ds;
    ds.d[0] = { W1,  W1T,  128, 128, 16384 };
    ds.d[1] = { Wx,  WxT,  128, 128, 16384 };
    ds.d[2] = { Wp1, Wp1T, 128, 128, 16384 };
    ds.d[3] = { Wv,  WvT,  256, 128, 32768 };
    ds.d[4] = { Wi,  WiT,  128, 384, 49152 };
    ds.d[5] = { Wh,  WhT,  128, 384, 49152 };
    k_wconv6<<<dim3(192, 6), dim3(256), 0, stream>>>(ds);
    k_w2c <<<dim3(64), dim3(256), 0, stream>>>(W2, Wc, W2cT);
    k_wcbp<<<dim3(64), dim3(256), 0, stream>>>(Wc, WcBP);

    (void)hipMemsetAsync(lp_acc, 0, 24 * sizeof(float), stream);
    (void)hipMemsetAsync(deg, 0, (size_t)NVAL * sizeof(int), stream);
    k_hist <<<dim3(625), dim3(256), 0, stream>>>(val_idx, deg);
    k_scan1<<<dim3(625), dim3(256), 0, stream>>>(deg, bsum);
    k_scan2<<<1, 1, 0, stream>>>(bsum, boff, 625);
    k_scan3<<<dim3(625), dim3(256), 0, stream>>>(deg, boff, off, cursor);
    k_place<<<dim3(625), dim3(256), 0, stream>>>(val_idx, cursor, inv);

    const dim3 B256(256);
    const dim3 gA(1280);       // K=128 GEMMs over NVAL
    const dim3 gW(320);        // small GEMM over NCST
    const dim3 gXU(512);       // fused x_val->uV
    const dim3 gB(2048);       // Z8 (col-half = bid&1)
    const dim3 gG(4 * GRU_NRB);// gruN: 4 col groups x 192 row blocks = 768
    const dim3 gS(2048);       // gather
    const dim3 gVar((NVAR + 255) / 256);
    const float* w1r128 = W1 + (size_t)128 * HD;

    k_init_hb<<<dim3(NVAL * HD / 256), B256, 0, stream>>>(hbA, h_init);
    k_sample0<<<gVar, B256, 0, stream>>>(gum, assign, lp_acc);
    k_unsat<<<gVar, B256, 0, stream>>>(assign, val_idx, sat);
    k_finalize<<<1, 1, 0, stream>>>(lp_acc, sat, best, out, 0, S, 0);

    for (int s = 0; s < S; ++s) {
        const int t = s + 1;
        const short* hcur = (s & 1) ? hbB : hbA;
        short*       hnxt = (s & 1) ? hbA : hbB;
        // 1. s_cst = sum8(relu([h[val_idx] | bit] @ W1 + b1))
        k_gemmA<AM_GATHER, true, true, EPI_RCST><<<gA, B256, 0, stream>>>(
            hcur, val_idx, assign, w1r128, W1T, b1, nullptr, s_cst, NVAL);
        // 2. r2c = s_cst @ (W2 @ WcTop)
        k_gemmA<AM_DIRECT, false, false, EPI_STORE><<<gW, B256, 0, stream>>>(
            s_cst, nullptr, nullptr, nullptr, W2cT, nullptr, r2c, nullptr, NCST);
        // 3. uV = relu(h @ Wx + bx) @ WcBot   (fused)
        k_gemmXU<<<gXU, B256, 0, stream>>>(hcur, WxT, WcBP, bx, uV);
        // 4. yV = wave-uniform CSR gather of relu(r2c + uV + bc)
        k_gather<<<gS, B256, 0, stream>>>(r2c, uV, off, inv, bc, yV);
        // 5+6. tA = z = relu([yV | mean8(yV)] @ Wv + bv)
        k_gemmZ8<<<gB, B256, 0, stream>>>(yV, WvT, bv, tA);
        // 7. hnxt = GRU(z, hcur)   (R=4, 512-thr, full prefetch, 3 blk/CU)
        k_gruN<<<gG, dim3(512), 0, stream>>>(tA, hcur, hnxt, WiT, WhT, bi, bh);
        // 8+9a. policy + in-wave sample -> assign, lp
        k_polS<<<gA, B256, 0, stream>>>(hnxt, Wp1T, bp1, Wp2,
                                        gum + (size_t)t * NVAL, assign, lp_acc + t);
        // 9b. unsat + outputs
        k_unsat<<<gVar, B256, 0, stream>>>(assign, val_idx, sat + t);
        k_finalize<<<1, 1, 0, stream>>>(lp_acc + t, sat + t, best, out, s, S, 1);
    }
}